// Round 2
// baseline (977.591 us; speedup 1.0000x reference)
//
#include <hip/hip_runtime.h>

// Problem: inputs [16,256,64,64] f32, embedding [2048,256] f32
#define KCODES  2048
#define DDIM    256

// d_out float-element offsets (return order: loss, quantized, perplexity, encodings)
#define OUT_LOSS 0
#define OUT_Q    1
#define OUT_PERP 16777217
#define OUT_ENC  16777218

// d_ws byte offsets (all scratch lives in ws now; enc region is written only by k_out)
#define WS_IDX  0              // int   idx[65536]        (256 KB)
#define WS_E2   1048576        // float e2[2048]          (8 KB)
#define WS_CNT  1056768        // int   counts[2048]      (8 KB)
#define WS_SUM  1064960        // float sumsq[1]
#define WS_EHI  2097152        // _Float16 Ehi[2048*256]  (1 MiB)

typedef _Float16 f16x8 __attribute__((ext_vector_type(8)));
typedef _Float16 f16x4 __attribute__((ext_vector_type(4)));
typedef float    f32x4 __attribute__((ext_vector_type(4)));
typedef float    f32x2 __attribute__((ext_vector_type(2)));

// top-2 pair merge with idx tie-break (lower idx wins)
#define MERGE2(m1,i1,m2,i2,n1,j1,n2,j2)                                   \
    {                                                                     \
        const bool w_ = ((n1) < (m1)) || ((n1) == (m1) && (j1) < (i1));   \
        const float w1_ = w_ ? (n1) : (m1); const int wi_ = w_ ? (j1) : (i1); \
        const float l1_ = w_ ? (m1) : (n1); const int li_ = w_ ? (i1) : (j1); \
        const float c2_ = w_ ? (n2) : (m2); const int ci_ = w_ ? (j2) : (i2); \
        const bool s_ = ((c2_) < (l1_)) || ((c2_) == (l1_) && (ci_) < (li_)); \
        (m1) = w1_; (i1) = wi_;                                           \
        (m2) = s_ ? c2_ : l1_; (i2) = s_ ? ci_ : li_;                     \
    }

// ------------------------------------------------ Ehi + ||e||^2 + zero counts/sumsq
__launch_bounds__(256)
__global__ void k_e2split(const float* __restrict__ emb, _Float16* __restrict__ Ehi,
                          float* __restrict__ e2, int* __restrict__ counts,
                          float* __restrict__ sumsq) {
    const int wave = threadIdx.x >> 6;
    const int lane = threadIdx.x & 63;
    const int k = blockIdx.x * 4 + wave;          // 512 blocks
    const float4 v = *(const float4*)(emb + k * DDIM + lane * 4);
    f16x4 h;
    h[0] = (_Float16)v.x; h[1] = (_Float16)v.y; h[2] = (_Float16)v.z; h[3] = (_Float16)v.w;
    *(f16x4*)(Ehi + k * DDIM + lane * 4) = h;
    float s = v.x * v.x + v.y * v.y + v.z * v.z + v.w * v.w;
#pragma unroll
    for (int off = 32; off >= 1; off >>= 1) s += __shfl_down(s, off);
    if (lane == 0) e2[k] = s;
    if (blockIdx.x < 8) counts[blockIdx.x * 256 + threadIdx.x] = 0;
    if (blockIdx.x == 8 && threadIdx.x == 0) sumsq[0] = 0.0f;
}

// ------------------------------------------------ fused main: f16 plane build (in-LDS) +
// approx top-4 (MFMA, B direct-from-L2, zero barriers in main loop) + exact refine +
// argmin + loss + counts. One block = 128 rows x all 2048 codes.
__launch_bounds__(256, 2)
__global__ void k_main(const float* __restrict__ inp, const float* __restrict__ emb,
                       const _Float16* __restrict__ Ehi, const float* __restrict__ e2g,
                       int* __restrict__ idx_g, int* __restrict__ counts,
                       float* __restrict__ sumsq) {
    __shared__ __align__(16) _Float16 A[128 * 256];   // 64 KB persistent f16 A-tile
    __shared__ float e2s[KCODES];                     // 8 KB
    __shared__ float xpart[4][128];                   // 2 KB ||x||^2 partials

    const int rb  = blockIdx.x;           // 512 blocks of 128 rows
    const int b   = rb >> 5;
    const int hw0 = (rb & 31) << 7;
    const int n0  = rb << 7;
    const int tid = threadIdx.x;
    const int w = tid >> 6, lane = tid & 63;
    const int lq = lane >> 4, lm = lane & 15;
    const int wr = (w >> 1) * 64, wc = (w & 1) * 64;  // wave quadrant

    // e2 -> LDS (2048 floats)
    {
        const float4* s = (const float4*)e2g;
        float4* d = (float4*)e2s;
        d[tid] = s[tid];
        d[tid + 256] = s[tid + 256];
    }

    // ---- prologue: inp[b, d, hw0+row] f32 -> swizzled f16 A[row][d] + x2 partials.
    // round rr: row = (rr&1)*64+lane, 8-d chunk cg = (rr>>1)*4 + w. Coalesced 256B loads.
    const float* base = inp + (size_t)b * 1048576 + hw0;
    float x2lo = 0.f, x2hi = 0.f;
#pragma unroll 4
    for (int rr = 0; rr < 16; ++rr) {
        const int row = ((rr & 1) << 6) + lane;
        const int cg  = ((rr >> 1) << 2) + w;
        const float* p = base + (size_t)(cg << 3) * 4096 + row;
        float v[8];
#pragma unroll
        for (int j = 0; j < 8; ++j) v[j] = p[(size_t)j * 4096];
        f16x8 h;
        float s = 0.f;
#pragma unroll
        for (int j = 0; j < 8; ++j) { h[j] = (_Float16)v[j]; s = fmaf(v[j], v[j], s); }
        if (rr & 1) x2hi += s; else x2lo += s;
        const int q  = cg >> 3;            // 64-d quarter
        const int ch = cg & 7;             // chunk within quarter
        // swizzle matches fragment read: chunk ch of row lives at (ch ^ (row&7))
        *(f16x8*)&A[row * 256 + q * 64 + ((ch ^ (row & 7)) << 3)] = h;
    }
    xpart[w][lane] = x2lo;
    xpart[w][64 + lane] = x2hi;
    __syncthreads();

    // ---- main loop: 16 col-tiles x 128 cols. A from LDS, B direct from Ehi (L2-hot),
    // 1-deep B prefetch, NO barriers.
    const _Float16* Bb = Ehi + (size_t)(wc + lm) * 256 + lq * 8;
    const int sw0 = ((lq    ) ^ (lm & 7)) << 3;   // s=0 fragment swizzle
    const int sw1 = ((lq ^ 4) ^ (lm & 7)) << 3;   // s=1

    float V1[4][4], V2[4][4]; int I1[4][4], I2[4][4];
#pragma unroll
    for (int i = 0; i < 4; ++i)
#pragma unroll
        for (int rr = 0; rr < 4; ++rr) {
            V1[i][rr] = 3.402823466e38f; V2[i][rr] = 3.402823466e38f;
            I1[i][rr] = 0x7fffffff;      I2[i][rr] = 0x7fffffff;
        }

#pragma unroll 1
    for (int ct = 0; ct < 16; ++ct) {
        const int c0 = ct * 128;
        f32x4 acc[4][4];
#pragma unroll
        for (int i = 0; i < 4; ++i)
#pragma unroll
            for (int j = 0; j < 4; ++j) acc[i][j] = (f32x4)(0.0f);

        f16x8 bn[4];
#pragma unroll
        for (int t = 0; t < 4; ++t)
            bn[t] = *(const f16x8*)(Bb + (size_t)(c0 + t * 16) * 256);

#pragma unroll
        for (int g = 0; g < 8; ++g) {     // g = kt*2 + s
            f16x8 bf[4];
#pragma unroll
            for (int t = 0; t < 4; ++t) bf[t] = bn[t];
            if (g < 7) {
                const int dof = (((g + 1) >> 1) << 6) + (((g + 1) & 1) << 5);
#pragma unroll
                for (int t = 0; t < 4; ++t)
                    bn[t] = *(const f16x8*)(Bb + (size_t)(c0 + t * 16) * 256 + dof);
            }
            const int kt = g >> 1;
            const int sw = (g & 1) ? sw1 : sw0;
            f16x8 af[4];
#pragma unroll
            for (int t = 0; t < 4; ++t)
                af[t] = *(const f16x8*)&A[(wr + t * 16 + lm) * 256 + kt * 64 + sw];
#pragma unroll
            for (int i = 0; i < 4; ++i)
#pragma unroll
                for (int j = 0; j < 4; ++j)
                    acc[i][j] = __builtin_amdgcn_mfma_f32_16x16x32_f16(af[i], bf[j], acc[i][j], 0, 0, 0);
        }

        // per-ct epilogue: branch-free running top-2. C layout: col=lm, row=lq*4+reg.
        float e2v[4];
#pragma unroll
        for (int j = 0; j < 4; ++j) e2v[j] = e2s[c0 + wc + j * 16 + lm];
#pragma unroll
        for (int i = 0; i < 4; ++i)
#pragma unroll
            for (int j = 0; j < 4; ++j) {
                const int idx = c0 + wc + j * 16 + lm;
#pragma unroll
                for (int rr = 0; rr < 4; ++rr) {
                    const float dist = fmaf(-2.0f, acc[i][j][rr], e2v[j]);
                    const bool b1 = dist < V1[i][rr];
                    const bool b2 = dist < V2[i][rr];
                    V2[i][rr] = b1 ? V1[i][rr] : (b2 ? dist : V2[i][rr]);
                    I2[i][rr] = b1 ? I1[i][rr] : (b2 ? idx  : I2[i][rr]);
                    V1[i][rr] = b1 ? dist : V1[i][rr];
                    I1[i][rr] = b1 ? idx  : I1[i][rr];
                }
            }
    }

    __syncthreads();                       // A fragment reads done -> safe to alias
    float4* red  = (float4*)&A[0];         // [128][2] candidate pairs (4 KB)
    float*  refp = (float*)&A[4096];       // [4][64][4] refine partials (byte 8192)
#pragma unroll
    for (int i = 0; i < 4; ++i)
#pragma unroll
        for (int rr = 0; rr < 4; ++rr) {
            float m1 = V1[i][rr]; int i1 = I1[i][rr];
            float m2 = V2[i][rr]; int i2 = I2[i][rr];
#pragma unroll
            for (int off = 1; off < 16; off <<= 1) {
                const float n1 = __shfl_xor(m1, off); const int j1 = __shfl_xor(i1, off);
                const float n2 = __shfl_xor(m2, off); const int j2 = __shfl_xor(i2, off);
                MERGE2(m1, i1, m2, i2, n1, j1, n2, j2);
            }
            if (lm == 0) {
                const int row = wr + i * 16 + lq * 4 + rr;
                red[row * 2 + (w & 1)] = make_float4(m1, __int_as_float(i1),
                                                     m2, __int_as_float(i2));
            }
        }
    __syncthreads();

    // ---- exact refine: wave w -> row group (w&1), d-half (w>>1). Coalesced inp reads.
    {
        const int rg = w & 1, dh = w >> 1;
        const int r  = (rg << 6) + lane;
        const float4 Ac = red[r * 2];
        const float4 Bc = red[r * 2 + 1];
        const int c0i = __float_as_int(Ac.y), c1i = __float_as_int(Ac.w);
        const int c2i = __float_as_int(Bc.y), c3i = __float_as_int(Bc.w);
        const float* xp = base + (size_t)(dh * 128) * 4096 + r;
        const float* p0 = emb + (size_t)c0i * DDIM + dh * 128;
        const float* p1 = emb + (size_t)c1i * DDIM + dh * 128;
        const float* p2 = emb + (size_t)c2i * DDIM + dh * 128;
        const float* p3 = emb + (size_t)c3i * DDIM + dh * 128;
        float s0 = 0.f, s1 = 0.f, s2 = 0.f, s3 = 0.f;
#pragma unroll 8
        for (int dd = 0; dd < 128; ++dd) {
            const float xv = xp[(size_t)dd * 4096];
            s0 = fmaf(xv, p0[dd], s0);
            s1 = fmaf(xv, p1[dd], s1);
            s2 = fmaf(xv, p2[dd], s2);
            s3 = fmaf(xv, p3[dd], s3);
        }
        f32x4 sv; sv[0] = s0; sv[1] = s1; sv[2] = s2; sv[3] = s3;
        *(f32x4*)&refp[(w * 64 + lane) * 4] = sv;
    }
    __syncthreads();

    // ---- finalize: pick best of 4, write idx, counts, loss
    if (tid < 128) {
        const int r = tid;
        const int g = r >> 6, rl = r & 63;
        float S[4];
#pragma unroll
        for (int k = 0; k < 4; ++k)
            S[k] = refp[(g * 64 + rl) * 4 + k] + refp[((g + 2) * 64 + rl) * 4 + k];
        const float4 Ac = red[r * 2];
        const float4 Bc = red[r * 2 + 1];
        const int cid[4] = {__float_as_int(Ac.y), __float_as_int(Ac.w),
                            __float_as_int(Bc.y), __float_as_int(Bc.w)};
        float bv = 3.402823466e38f; int bi = 0; float sb = 0.f, eb = 0.f;
#pragma unroll
        for (int k = 0; k < 4; ++k) {
            const float ev = e2s[cid[k]];
            const float dv = fmaf(-2.0f, S[k], ev);
            if (dv < bv || (dv == bv && cid[k] < bi)) { bv = dv; bi = cid[k]; sb = S[k]; eb = ev; }
        }
        idx_g[n0 + r] = bi;
        atomicAdd(&counts[bi], 1);
        const float x2r = xpart[0][r] + xpart[1][r] + xpart[2][r] + xpart[3][r];
        float lr = x2r - 2.0f * sb + eb;   // ||x - q||^2
#pragma unroll
        for (int off = 32; off >= 1; off >>= 1) lr += __shfl_down(lr, off);
        if ((r & 63) == 0) atomicAdd(sumsq, lr);
    }
}

// ------------------------------------------------ pure output kernel: gather quantized +
// one-hot encodings, nontemporal (write-once streams). Block = 64 rows.
__launch_bounds__(256)
__global__ void k_out(const float* __restrict__ emb, const int* __restrict__ idx_g,
                      float* __restrict__ outQ, float* __restrict__ enc) {
    __shared__ int idxs[64];
    const int blk = blockIdx.x;            // 1024 blocks
    const int b   = blk >> 6;
    const int hw0 = (blk & 63) << 6;
    const int w = threadIdx.x >> 6, lane = threadIdx.x & 63;
    const int n0 = (b << 12) + hw0;

    if (threadIdx.x < 64) idxs[threadIdx.x] = idx_g[n0 + threadIdx.x];
    __syncthreads();

    // quantized: gather emb rows (L2-hot), coalesced 256B nt stores
    const int myidx = idxs[lane];
    const float* qp = emb + (size_t)myidx * DDIM + w * 64;
    float* op = outQ + (size_t)b * 1048576 + (size_t)(w * 64) * 4096 + hw0 + lane;
#pragma unroll 8
    for (int dd = 0; dd < 64; ++dd)
        __builtin_nontemporal_store(qp[dd], op + (size_t)dd * 4096);

    // one-hot encodings (64 rows x 8 KB), 8B-aligned f32x2 nt stores
    f32x2* erow = (f32x2*)enc + (size_t)n0 * 1024;
#pragma unroll 1
    for (int rr = 0; rr < 64; ++rr) {
        const int id = idxs[rr];
        f32x2* rp = erow + (size_t)rr * 1024;
#pragma unroll
        for (int k = 0; k < 4; ++k) {
            const int c2 = k * 256 + threadIdx.x;
            const int ccc = c2 * 2;
            f32x2 v;
            v[0] = (ccc == id) ? 1.0f : 0.0f;
            v[1] = (ccc + 1 == id) ? 1.0f : 0.0f;
            __builtin_nontemporal_store(v, rp + c2);
        }
    }
}

// ------------------------------------------------ scalars
__launch_bounds__(256)
__global__ void k_finalize(const int* __restrict__ counts, const float* __restrict__ sumsq,
                           float* __restrict__ out) {
    __shared__ float red[256];
    const int t = threadIdx.x;
    float s = 0.0f;
    for (int k = t; k < KCODES; k += 256) {
        const float p = (float)counts[k] * (1.0f / 65536.0f);
        s += p * logf(p + 1e-10f);
    }
    red[t] = s;
    __syncthreads();
    for (int off = 128; off >= 1; off >>= 1) {
        if (t < off) red[t] += red[t + off];
        __syncthreads();
    }
    if (t == 0) {
        out[OUT_PERP] = expf(-red[0]);
        out[OUT_LOSS] = 0.25f * sumsq[0] * (1.0f / 16777216.0f);
    }
}

// ------------------------------------------------ launch
extern "C" void kernel_launch(void* const* d_in, const int* in_sizes, int n_in,
                              void* d_out, int out_size, void* d_ws, size_t ws_size,
                              hipStream_t stream) {
    const float* inp = (const float*)d_in[0];
    const float* emb = (const float*)d_in[1];
    float* out = (float*)d_out;
    char* wsb  = (char*)d_ws;

    int*      idxg   = (int*)(wsb + WS_IDX);
    float*    e2     = (float*)(wsb + WS_E2);
    int*      counts = (int*)(wsb + WS_CNT);
    float*    sumsq  = (float*)(wsb + WS_SUM);
    _Float16* Ehi    = (_Float16*)(wsb + WS_EHI);

    k_e2split <<<512,  256, 0, stream>>>(emb, Ehi, e2, counts, sumsq);
    k_main    <<<512,  256, 0, stream>>>(inp, emb, Ehi, e2, idxg, counts, sumsq);
    k_out     <<<1024, 256, 0, stream>>>(emb, idxg, out + OUT_Q, out + OUT_ENC);
    k_finalize<<<1,    256, 0, stream>>>(counts, sumsq, out);
}

// Round 3
// 892.574 us; speedup vs baseline: 1.0952x; 1.0952x over previous
//
#include <hip/hip_runtime.h>

// Problem: inputs [16,256,64,64] f32, embedding [2048,256] f32
#define KCODES  2048
#define DDIM    256

// d_out float-element offsets (return order: loss, quantized, perplexity, encodings)
#define OUT_LOSS 0
#define OUT_Q    1
#define OUT_PERP 16777217
#define OUT_ENC  16777218

// d_ws byte offsets
#define WS_IDX  0              // int   idx[65536]        (256 KB)
#define WS_E2   1048576        // float e2[2048]          (8 KB)
#define WS_CNT  1056768        // int   counts[2048]      (8 KB)
#define WS_SUM  1064960        // float sumsq[1]
#define WS_EHI  2097152        // _Float16 Ehi[2048*256]  (1 MiB)

typedef _Float16 f16x8 __attribute__((ext_vector_type(8)));
typedef _Float16 f16x4 __attribute__((ext_vector_type(4)));
typedef float    f32x4 __attribute__((ext_vector_type(4)));
typedef float    f32x2 __attribute__((ext_vector_type(2)));

__device__ __forceinline__ void gld16(const void* g, void* l) {
    __builtin_amdgcn_global_load_lds((const __attribute__((address_space(1))) void*)g,
                                     (__attribute__((address_space(3))) void*)l, 16, 0, 0);
}

// top-2 pair merge with idx tie-break (lower idx wins)
#define MERGE2(m1,i1,m2,i2,n1,j1,n2,j2)                                   \
    {                                                                     \
        const bool w_ = ((n1) < (m1)) || ((n1) == (m1) && (j1) < (i1));   \
        const float w1_ = w_ ? (n1) : (m1); const int wi_ = w_ ? (j1) : (i1); \
        const float l1_ = w_ ? (m1) : (n1); const int li_ = w_ ? (i1) : (j1); \
        const float c2_ = w_ ? (n2) : (m2); const int ci_ = w_ ? (j2) : (i2); \
        const bool s_ = ((c2_) < (l1_)) || ((c2_) == (l1_) && (ci_) < (li_)); \
        (m1) = w1_; (i1) = wi_;                                           \
        (m2) = s_ ? c2_ : l1_; (i2) = s_ ? ci_ : li_;                     \
    }

// ------------------------------------------------ Ehi + ||e||^2 + zero counts/sumsq
__launch_bounds__(256)
__global__ void k_e2split(const float* __restrict__ emb, _Float16* __restrict__ Ehi,
                          float* __restrict__ e2, int* __restrict__ counts,
                          float* __restrict__ sumsq) {
    const int wave = threadIdx.x >> 6;
    const int lane = threadIdx.x & 63;
    const int k = blockIdx.x * 4 + wave;          // 512 blocks
    const float4 v = *(const float4*)(emb + k * DDIM + lane * 4);
    f16x4 h;
    h[0] = (_Float16)v.x; h[1] = (_Float16)v.y; h[2] = (_Float16)v.z; h[3] = (_Float16)v.w;
    *(f16x4*)(Ehi + k * DDIM + lane * 4) = h;
    float s = v.x * v.x + v.y * v.y + v.z * v.z + v.w * v.w;
#pragma unroll
    for (int off = 32; off >= 1; off >>= 1) s += __shfl_down(s, off);
    if (lane == 0) e2[k] = s;
    if (blockIdx.x < 8) counts[blockIdx.x * 256 + threadIdx.x] = 0;
    if (blockIdx.x == 8 && threadIdx.x == 0) sumsq[0] = 0.0f;
}

// ------------------------------------------------ fused main: f16 A-plane built in-LDS
// (persistent, 64 KB) + approx top-4 via MFMA with B staged per-kt through LDS via
// global_load_lds (the baseline-verified pipeline, now half the staging volume) +
// exact refine + argmin + loss + counts. One block = 128 rows x all 2048 codes.
__launch_bounds__(256, 2)
__global__ void k_main(const float* __restrict__ inp, const float* __restrict__ emb,
                       const _Float16* __restrict__ Ehi, const float* __restrict__ e2g,
                       int* __restrict__ idx_g, int* __restrict__ counts,
                       float* __restrict__ sumsq) {
    __shared__ __align__(16) _Float16 A[128 * 256];   // 64 KB persistent f16 A-tile
    __shared__ __align__(16) _Float16 Bh[128 * 64];   // 16 KB B kt-stage  (total 80 KB)

    const int rb  = blockIdx.x;           // 512 blocks of 128 rows
    const int b   = rb >> 5;
    const int hw0 = (rb & 31) << 7;
    const int n0  = rb << 7;
    const int tid = threadIdx.x;
    const int w = tid >> 6, lane = tid & 63;
    const int lq = lane >> 4, lm = lane & 15;
    const int wr = (w >> 1) * 64, wc = (w & 1) * 64;  // wave quadrant
    const int r8 = lane >> 3, c8 = lane & 7;
    const int gch = c8 ^ r8;              // XOR-swizzled source chunk for B staging

    // ---- prologue: inp[b, d, hw0+row] f32 -> swizzled f16 A[row][d]. Coalesced 256B loads.
    const float* base = inp + (size_t)b * 1048576 + hw0;
#pragma unroll 4
    for (int rr = 0; rr < 16; ++rr) {
        const int row = ((rr & 1) << 6) + lane;
        const int cg  = ((rr >> 1) << 2) + w;
        const float* p = base + (size_t)(cg << 3) * 4096 + row;
        float v[8];
#pragma unroll
        for (int j = 0; j < 8; ++j) v[j] = p[(size_t)j * 4096];
        f16x8 h;
#pragma unroll
        for (int j = 0; j < 8; ++j) h[j] = (_Float16)v[j];
        const int q  = cg >> 3;            // 64-d quarter
        const int ch = cg & 7;             // chunk within quarter
        // swizzle matches fragment read: chunk ch of row lives at (ch ^ (row&7))
        *(f16x8*)&A[row * 256 + q * 64 + ((ch ^ (row & 7)) << 3)] = h;
    }
    __syncthreads();

    // ---- main loop: 16 col-tiles x 128 cols. A from persistent LDS; B staged per-kt
    // via global_load_lds (pre-swizzled source, linear LDS dest), 2 barriers/kt.
    const int sw0 = ((lq    ) ^ (lm & 7)) << 3;   // s=0 A-fragment swizzle
    const int sw1 = ((lq ^ 4) ^ (lm & 7)) << 3;   // s=1

    float V1[4][4], V2[4][4]; int I1[4][4], I2[4][4];
#pragma unroll
    for (int i = 0; i < 4; ++i)
#pragma unroll
        for (int rr = 0; rr < 4; ++rr) {
            V1[i][rr] = 3.402823466e38f; V2[i][rr] = 3.402823466e38f;
            I1[i][rr] = 0x7fffffff;      I2[i][rr] = 0x7fffffff;
        }

#pragma unroll 1
    for (int ct = 0; ct < 16; ++ct) {
        const int c0 = ct * 128;
        // e2 prefetch (L2-hot, consumed after 4 kt of MFMA work)
        float e2v[4];
#pragma unroll
        for (int j = 0; j < 4; ++j) e2v[j] = e2g[c0 + wc + j * 16 + lm];

        f32x4 acc[4][4];
#pragma unroll
        for (int i = 0; i < 4; ++i)
#pragma unroll
            for (int j = 0; j < 4; ++j) acc[i][j] = (f32x4)(0.0f);

#pragma unroll 1
        for (int kt = 0; kt < 4; ++kt) {
            const int d0 = kt * 64;
            __syncthreads();
#pragma unroll
            for (int i = 0; i < 4; ++i) {
                const int Row = i * 32 + w * 8 + r8;
                gld16(Ehi + (size_t)(c0 + Row) * DDIM + d0 + gch * 8, &Bh[(i * 32 + w * 8) * 64]);
            }
            __syncthreads();
#pragma unroll
            for (int s = 0; s < 2; ++s) {
                const int wch = s * 4 + lq;
                const int sw = s ? sw1 : sw0;
                f16x8 af[4], bf[4];
#pragma unroll
                for (int t = 0; t < 4; ++t) {
                    const int Rb = wc + t * 16 + lm;
                    af[t] = *(const f16x8*)&A[(wr + t * 16 + lm) * 256 + d0 + sw];
                    bf[t] = *(const f16x8*)&Bh[Rb * 64 + ((wch ^ (Rb & 7)) << 3)];
                }
#pragma unroll
                for (int i = 0; i < 4; ++i)
#pragma unroll
                    for (int j = 0; j < 4; ++j)
                        acc[i][j] = __builtin_amdgcn_mfma_f32_16x16x32_f16(af[i], bf[j], acc[i][j], 0, 0, 0);
            }
        }

        // per-ct epilogue: branch-free running top-2. C layout: col=lm, row=lq*4+reg.
#pragma unroll
        for (int i = 0; i < 4; ++i)
#pragma unroll
            for (int j = 0; j < 4; ++j) {
                const int idx = c0 + wc + j * 16 + lm;
#pragma unroll
                for (int rr = 0; rr < 4; ++rr) {
                    const float dist = fmaf(-2.0f, acc[i][j][rr], e2v[j]);
                    const bool b1 = dist < V1[i][rr];
                    const bool b2 = dist < V2[i][rr];
                    V2[i][rr] = b1 ? V1[i][rr] : (b2 ? dist : V2[i][rr]);
                    I2[i][rr] = b1 ? I1[i][rr] : (b2 ? idx  : I2[i][rr]);
                    V1[i][rr] = b1 ? dist : V1[i][rr];
                    I1[i][rr] = b1 ? idx  : I1[i][rr];
                }
            }
    }

    __syncthreads();                       // A fragment reads done -> safe to alias
    float4* red  = (float4*)&A[0];         // [128][2] candidate pairs (4 KB)
    float*  refp = (float*)&A[4096];       // [5][256] refine partials (byte 8192..13312)
#pragma unroll
    for (int i = 0; i < 4; ++i)
#pragma unroll
        for (int rr = 0; rr < 4; ++rr) {
            float m1 = V1[i][rr]; int i1 = I1[i][rr];
            float m2 = V2[i][rr]; int i2 = I2[i][rr];
#pragma unroll
            for (int off = 1; off < 16; off <<= 1) {
                const float n1 = __shfl_xor(m1, off); const int j1 = __shfl_xor(i1, off);
                const float n2 = __shfl_xor(m2, off); const int j2 = __shfl_xor(i2, off);
                MERGE2(m1, i1, m2, i2, n1, j1, n2, j2);
            }
            if (lm == 0) {
                const int row = wr + i * 16 + lq * 4 + rr;
                red[row * 2 + (w & 1)] = make_float4(m1, __int_as_float(i1),
                                                     m2, __int_as_float(i2));
            }
        }
    __syncthreads();

    // ---- exact refine: wave w -> row group (w&1), d-half (w>>1). Coalesced inp reads.
    // Also accumulates ||x||^2 (s4) on the same data.
    {
        const int rg = w & 1, dh = w >> 1;
        const int r  = (rg << 6) + lane;
        const float4 Ac = red[r * 2];
        const float4 Bc = red[r * 2 + 1];
        const int c0i = __float_as_int(Ac.y), c1i = __float_as_int(Ac.w);
        const int c2i = __float_as_int(Bc.y), c3i = __float_as_int(Bc.w);
        const float* xp = base + (size_t)(dh * 128) * 4096 + r;
        const float* p0 = emb + (size_t)c0i * DDIM + dh * 128;
        const float* p1 = emb + (size_t)c1i * DDIM + dh * 128;
        const float* p2 = emb + (size_t)c2i * DDIM + dh * 128;
        const float* p3 = emb + (size_t)c3i * DDIM + dh * 128;
        float s0 = 0.f, s1 = 0.f, s2 = 0.f, s3 = 0.f, s4 = 0.f;
#pragma unroll 8
        for (int dd = 0; dd < 128; ++dd) {
            const float xv = xp[(size_t)dd * 4096];
            s0 = fmaf(xv, p0[dd], s0);
            s1 = fmaf(xv, p1[dd], s1);
            s2 = fmaf(xv, p2[dd], s2);
            s3 = fmaf(xv, p3[dd], s3);
            s4 = fmaf(xv, xv,     s4);
        }
        refp[0 * 256 + w * 64 + lane] = s0;
        refp[1 * 256 + w * 64 + lane] = s1;
        refp[2 * 256 + w * 64 + lane] = s2;
        refp[3 * 256 + w * 64 + lane] = s3;
        refp[4 * 256 + w * 64 + lane] = s4;
    }
    __syncthreads();

    // ---- finalize: pick best of 4, write idx, counts, loss
    if (tid < 128) {
        const int r = tid;
        const int g = r >> 6, rl = r & 63;
        float S[5];
#pragma unroll
        for (int k = 0; k < 5; ++k)
            S[k] = refp[k * 256 + g * 64 + rl] + refp[k * 256 + (g + 2) * 64 + rl];
        const float4 Ac = red[r * 2];
        const float4 Bc = red[r * 2 + 1];
        const int cid[4] = {__float_as_int(Ac.y), __float_as_int(Ac.w),
                            __float_as_int(Bc.y), __float_as_int(Bc.w)};
        float bv = 3.402823466e38f; int bi = 0; float sb = 0.f, eb = 0.f;
#pragma unroll
        for (int k = 0; k < 4; ++k) {
            const float ev = e2g[cid[k]];
            const float dv = fmaf(-2.0f, S[k], ev);
            if (dv < bv || (dv == bv && cid[k] < bi)) { bv = dv; bi = cid[k]; sb = S[k]; eb = ev; }
        }
        idx_g[n0 + r] = bi;
        atomicAdd(&counts[bi], 1);
        float lr = S[4] - 2.0f * sb + eb;   // ||x - q||^2
#pragma unroll
        for (int off = 32; off >= 1; off >>= 1) lr += __shfl_down(lr, off);
        if ((r & 63) == 0) atomicAdd(sumsq, lr);
    }
}

// ------------------------------------------------ pure output kernel: gather quantized +
// one-hot encodings, nontemporal (write-once streams). Block = 64 rows.
__launch_bounds__(256)
__global__ void k_out(const float* __restrict__ emb, const int* __restrict__ idx_g,
                      float* __restrict__ outQ, float* __restrict__ enc) {
    __shared__ int idxs[64];
    const int blk = blockIdx.x;            // 1024 blocks
    const int b   = blk >> 6;
    const int hw0 = (blk & 63) << 6;
    const int w = threadIdx.x >> 6, lane = threadIdx.x & 63;
    const int n0 = (b << 12) + hw0;

    if (threadIdx.x < 64) idxs[threadIdx.x] = idx_g[n0 + threadIdx.x];
    __syncthreads();

    // quantized: gather emb rows (L2-hot), coalesced 256B nt stores
    const int myidx = idxs[lane];
    const float* qp = emb + (size_t)myidx * DDIM + w * 64;
    float* op = outQ + (size_t)b * 1048576 + (size_t)(w * 64) * 4096 + hw0 + lane;
#pragma unroll 8
    for (int dd = 0; dd < 64; ++dd)
        __builtin_nontemporal_store(qp[dd], op + (size_t)dd * 4096);

    // one-hot encodings (64 rows x 8 KB), 8B-aligned f32x2 nt stores
    f32x2* erow = (f32x2*)enc + (size_t)n0 * 1024;
#pragma unroll 1
    for (int rr = 0; rr < 64; ++rr) {
        const int id = idxs[rr];
        f32x2* rp = erow + (size_t)rr * 1024;
#pragma unroll
        for (int k = 0; k < 4; ++k) {
            const int c2 = k * 256 + threadIdx.x;
            const int ccc = c2 * 2;
            f32x2 v;
            v[0] = (ccc == id) ? 1.0f : 0.0f;
            v[1] = (ccc + 1 == id) ? 1.0f : 0.0f;
            __builtin_nontemporal_store(v, rp + c2);
        }
    }
}

// ------------------------------------------------ scalars
__launch_bounds__(256)
__global__ void k_finalize(const int* __restrict__ counts, const float* __restrict__ sumsq,
                           float* __restrict__ out) {
    __shared__ float red[256];
    const int t = threadIdx.x;
    float s = 0.0f;
    for (int k = t; k < KCODES; k += 256) {
        const float p = (float)counts[k] * (1.0f / 65536.0f);
        s += p * logf(p + 1e-10f);
    }
    red[t] = s;
    __syncthreads();
    for (int off = 128; off >= 1; off >>= 1) {
        if (t < off) red[t] += red[t + off];
        __syncthreads();
    }
    if (t == 0) {
        out[OUT_PERP] = expf(-red[0]);
        out[OUT_LOSS] = 0.25f * sumsq[0] * (1.0f / 16777216.0f);
    }
}

// ------------------------------------------------ launch
extern "C" void kernel_launch(void* const* d_in, const int* in_sizes, int n_in,
                              void* d_out, int out_size, void* d_ws, size_t ws_size,
                              hipStream_t stream) {
    const float* inp = (const float*)d_in[0];
    const float* emb = (const float*)d_in[1];
    float* out = (float*)d_out;
    char* wsb  = (char*)d_ws;

    int*      idxg   = (int*)(wsb + WS_IDX);
    float*    e2     = (float*)(wsb + WS_E2);
    int*      counts = (int*)(wsb + WS_CNT);
    float*    sumsq  = (float*)(wsb + WS_SUM);
    _Float16* Ehi    = (_Float16*)(wsb + WS_EHI);

    k_e2split <<<512,  256, 0, stream>>>(emb, Ehi, e2, counts, sumsq);
    k_main    <<<512,  256, 0, stream>>>(inp, emb, Ehi, e2, idxg, counts, sumsq);
    k_out     <<<1024, 256, 0, stream>>>(emb, idxg, out + OUT_Q, out + OUT_ENC);
    k_finalize<<<1,    256, 0, stream>>>(counts, sumsq, out);
}

// Round 4
// 858.028 us; speedup vs baseline: 1.1393x; 1.0403x over previous
//
#include <hip/hip_runtime.h>

// Problem: inputs [16,256,64,64] f32, embedding [2048,256] f32
#define KCODES  2048
#define DDIM    256

// d_out float-element offsets (return order: loss, quantized, perplexity, encodings)
#define OUT_LOSS 0
#define OUT_Q    1
#define OUT_PERP 16777217
#define OUT_ENC  16777218

// d_ws byte offsets
#define WS_IDX  0              // int   idx[65536]        (256 KB)
#define WS_E2   1048576        // float e2[2048]          (8 KB)
#define WS_CNT  1056768        // int   counts[2048]      (8 KB)
#define WS_SUM  1064960        // float sumsq[1]
#define WS_EHI  2097152        // _Float16 Ehi[2048*256]  (1 MiB)

typedef _Float16 f16x8 __attribute__((ext_vector_type(8)));
typedef _Float16 f16x4 __attribute__((ext_vector_type(4)));
typedef float    f32x4 __attribute__((ext_vector_type(4)));
typedef float    f32x2 __attribute__((ext_vector_type(2)));

__device__ __forceinline__ void gld16(const void* g, void* l) {
    __builtin_amdgcn_global_load_lds((const __attribute__((address_space(1))) void*)g,
                                     (__attribute__((address_space(3))) void*)l, 16, 0, 0);
}

// top-2 pair merge with idx tie-break (lower idx wins)
#define MERGE2(m1,i1,m2,i2,n1,j1,n2,j2)                                   \
    {                                                                     \
        const bool w_ = ((n1) < (m1)) || ((n1) == (m1) && (j1) < (i1));   \
        const float w1_ = w_ ? (n1) : (m1); const int wi_ = w_ ? (j1) : (i1); \
        const float l1_ = w_ ? (m1) : (n1); const int li_ = w_ ? (i1) : (j1); \
        const float c2_ = w_ ? (n2) : (m2); const int ci_ = w_ ? (j2) : (i2); \
        const bool s_ = ((c2_) < (l1_)) || ((c2_) == (l1_) && (ci_) < (li_)); \
        (m1) = w1_; (i1) = wi_;                                           \
        (m2) = s_ ? c2_ : l1_; (i2) = s_ ? ci_ : li_;                     \
    }

// ------------------------------------------------ Ehi + ||e||^2 + zero counts/sumsq
__launch_bounds__(256)
__global__ void k_e2split(const float* __restrict__ emb, _Float16* __restrict__ Ehi,
                          float* __restrict__ e2, int* __restrict__ counts,
                          float* __restrict__ sumsq) {
    const int wave = threadIdx.x >> 6;
    const int lane = threadIdx.x & 63;
    const int k = blockIdx.x * 4 + wave;          // 512 blocks
    const float4 v = *(const float4*)(emb + k * DDIM + lane * 4);
    f16x4 h;
    h[0] = (_Float16)v.x; h[1] = (_Float16)v.y; h[2] = (_Float16)v.z; h[3] = (_Float16)v.w;
    *(f16x4*)(Ehi + k * DDIM + lane * 4) = h;
    float s = v.x * v.x + v.y * v.y + v.z * v.z + v.w * v.w;
#pragma unroll
    for (int off = 32; off >= 1; off >>= 1) s += __shfl_down(s, off);
    if (lane == 0) e2[k] = s;
    if (blockIdx.x < 8) counts[blockIdx.x * 256 + threadIdx.x] = 0;
    if (blockIdx.x == 8 && threadIdx.x == 0) sumsq[0] = 0.0f;
}

// ------------------------------------------------ fused main: f16 A-plane in-LDS +
// approx top-4 (identical GEMM to prev round) + COALESCED exact refine (16-lane group
// per row; emb reads contiguous per group) + argmin + loss + counts.
__launch_bounds__(256, 2)
__global__ void k_main(const float* __restrict__ inp, const float* __restrict__ emb,
                       const _Float16* __restrict__ Ehi, const float* __restrict__ e2g,
                       int* __restrict__ idx_g, int* __restrict__ counts,
                       float* __restrict__ sumsq) {
    __shared__ __align__(16) char pool[81920];        // 80 KB union
    _Float16* A  = (_Float16*)pool;                   // [128*256] f16, 64 KB (GEMM phase)
    _Float16* Bh = (_Float16*)(pool + 65536);         // [128*64]  f16, 16 KB (GEMM phase)

    const int rb  = blockIdx.x;           // 512 blocks of 128 rows
    const int b   = rb >> 5;
    const int hw0 = (rb & 31) << 7;
    const int n0  = rb << 7;
    const int tid = threadIdx.x;
    const int w = tid >> 6, lane = tid & 63;
    const int lq = lane >> 4, lm = lane & 15;
    const int wr = (w >> 1) * 64, wc = (w & 1) * 64;  // wave quadrant
    const int r8 = lane >> 3, c8 = lane & 7;
    const int gch = c8 ^ r8;              // XOR-swizzled source chunk for B staging

    // ---- prologue: inp[b, d, hw0+row] f32 -> swizzled f16 A[row][d]. Coalesced 256B loads.
    const float* base = inp + (size_t)b * 1048576 + hw0;
#pragma unroll 4
    for (int rr = 0; rr < 16; ++rr) {
        const int row = ((rr & 1) << 6) + lane;
        const int cg  = ((rr >> 1) << 2) + w;
        const float* p = base + (size_t)(cg << 3) * 4096 + row;
        float v[8];
#pragma unroll
        for (int j = 0; j < 8; ++j) v[j] = p[(size_t)j * 4096];
        f16x8 h;
#pragma unroll
        for (int j = 0; j < 8; ++j) h[j] = (_Float16)v[j];
        const int q  = cg >> 3;            // 64-d quarter
        const int ch = cg & 7;             // chunk within quarter
        *(f16x8*)&A[row * 256 + q * 64 + ((ch ^ (row & 7)) << 3)] = h;
    }
    __syncthreads();

    // ---- main loop: 16 col-tiles x 128 cols. A persistent LDS; B staged per-kt via
    // global_load_lds (pre-swizzled source, linear LDS dest), 2 barriers/kt.
    const int sw0 = ((lq    ) ^ (lm & 7)) << 3;   // s=0 A-fragment swizzle
    const int sw1 = ((lq ^ 4) ^ (lm & 7)) << 3;   // s=1

    float V1[4][4], V2[4][4]; int I1[4][4], I2[4][4];
#pragma unroll
    for (int i = 0; i < 4; ++i)
#pragma unroll
        for (int rr = 0; rr < 4; ++rr) {
            V1[i][rr] = 3.402823466e38f; V2[i][rr] = 3.402823466e38f;
            I1[i][rr] = 0x7fffffff;      I2[i][rr] = 0x7fffffff;
        }

#pragma unroll 1
    for (int ct = 0; ct < 16; ++ct) {
        const int c0 = ct * 128;
        float e2v[4];
#pragma unroll
        for (int j = 0; j < 4; ++j) e2v[j] = e2g[c0 + wc + j * 16 + lm];

        f32x4 acc[4][4];
#pragma unroll
        for (int i = 0; i < 4; ++i)
#pragma unroll
            for (int j = 0; j < 4; ++j) acc[i][j] = (f32x4)(0.0f);

#pragma unroll 1
        for (int kt = 0; kt < 4; ++kt) {
            const int d0 = kt * 64;
            __syncthreads();
#pragma unroll
            for (int i = 0; i < 4; ++i) {
                const int Row = i * 32 + w * 8 + r8;
                gld16(Ehi + (size_t)(c0 + Row) * DDIM + d0 + gch * 8, &Bh[(i * 32 + w * 8) * 64]);
            }
            __syncthreads();
#pragma unroll
            for (int s = 0; s < 2; ++s) {
                const int wch = s * 4 + lq;
                const int sw = s ? sw1 : sw0;
                f16x8 af[4], bf[4];
#pragma unroll
                for (int t = 0; t < 4; ++t) {
                    const int Rb = wc + t * 16 + lm;
                    af[t] = *(const f16x8*)&A[(wr + t * 16 + lm) * 256 + d0 + sw];
                    bf[t] = *(const f16x8*)&Bh[Rb * 64 + ((wch ^ (Rb & 7)) << 3)];
                }
#pragma unroll
                for (int i = 0; i < 4; ++i)
#pragma unroll
                    for (int j = 0; j < 4; ++j)
                        acc[i][j] = __builtin_amdgcn_mfma_f32_16x16x32_f16(af[i], bf[j], acc[i][j], 0, 0, 0);
            }
        }

        // per-ct epilogue: branch-free running top-2. C layout: col=lm, row=lq*4+reg.
#pragma unroll
        for (int i = 0; i < 4; ++i)
#pragma unroll
            for (int j = 0; j < 4; ++j) {
                const int idx = c0 + wc + j * 16 + lm;
#pragma unroll
                for (int rr = 0; rr < 4; ++rr) {
                    const float dist = fmaf(-2.0f, acc[i][j][rr], e2v[j]);
                    const bool b1 = dist < V1[i][rr];
                    const bool b2 = dist < V2[i][rr];
                    V2[i][rr] = b1 ? V1[i][rr] : (b2 ? dist : V2[i][rr]);
                    I2[i][rr] = b1 ? I1[i][rr] : (b2 ? idx  : I2[i][rr]);
                    V1[i][rr] = b1 ? dist : V1[i][rr];
                    I1[i][rr] = b1 ? idx  : I1[i][rr];
                }
            }
    }

    __syncthreads();                       // GEMM LDS reads done -> pool reusable
    float4* red  = (float4*)pool;          // [128][2] candidate pairs (4 KB)
    float*  lsum = (float*)(pool + 4096);  // block loss accumulator
    float*  xf   = (float*)(pool + 8192);  // [128 dloc][129 rows] f32 (66 KB)
#pragma unroll
    for (int i = 0; i < 4; ++i)
#pragma unroll
        for (int rr = 0; rr < 4; ++rr) {
            float m1 = V1[i][rr]; int i1 = I1[i][rr];
            float m2 = V2[i][rr]; int i2 = I2[i][rr];
#pragma unroll
            for (int off = 1; off < 16; off <<= 1) {
                const float n1 = __shfl_xor(m1, off); const int j1 = __shfl_xor(i1, off);
                const float n2 = __shfl_xor(m2, off); const int j2 = __shfl_xor(i2, off);
                MERGE2(m1, i1, m2, i2, n1, j1, n2, j2);
            }
            if (lm == 0) {
                const int row = wr + i * 16 + lq * 4 + rr;
                red[row * 2 + (w & 1)] = make_float4(m1, __int_as_float(i1),
                                                     m2, __int_as_float(i2));
            }
        }
    if (tid == 0) *lsum = 0.f;

    // ---- COALESCED exact refine: 16-lane group per row; lane lm covers d-chunk lm*8..+7.
    // x staged in f32 LDS (transposed, conflict-free); emb reads contiguous 512B per group.
    const int g16 = tid >> 4;              // 16 groups, each owns rows g16*8 .. +7
    float Sp[8][4], X2r[8];
#pragma unroll
    for (int rr = 0; rr < 8; ++rr) {
        X2r[rr] = 0.f;
#pragma unroll
        for (int c = 0; c < 4; ++c) Sp[rr][c] = 0.f;
    }

#pragma unroll 1
    for (int h = 0; h < 2; ++h) {
        __syncthreads();                   // prev phase reads done (merge / h=0 compute)
        // stage xf[dloc][row] for d in [h*128, h*128+128); wave w owns dloc w*32..+31
#pragma unroll 8
        for (int k2 = 0; k2 < 32; ++k2) {
            const int dloc = w * 32 + k2;
            const float* sp = base + (size_t)(h * 128 + dloc) * 4096;
            xf[dloc * 129 + lane]      = sp[lane];
            xf[dloc * 129 + 64 + lane] = sp[64 + lane];
        }
        __syncthreads();
#pragma unroll
        for (int rr = 0; rr < 8; ++rr) {
            const int r = g16 * 8 + rr;
            const float4 Ac = red[r * 2];
            const float4 Bc = red[r * 2 + 1];
            const int cid[4] = {__float_as_int(Ac.y), __float_as_int(Ac.w),
                                __float_as_int(Bc.y), __float_as_int(Bc.w)};
            float x8[8];
#pragma unroll
            for (int j = 0; j < 8; ++j) x8[j] = xf[(lm * 8 + j) * 129 + r];
#pragma unroll
            for (int j = 0; j < 8; ++j) X2r[rr] = fmaf(x8[j], x8[j], X2r[rr]);
#pragma unroll
            for (int c = 0; c < 4; ++c) {
                const float* ep = emb + (size_t)cid[c] * DDIM + h * 128 + lm * 8;
                const float4 e0 = *(const float4*)ep;
                const float4 e1 = *(const float4*)(ep + 4);
                float s = Sp[rr][c];
                s = fmaf(x8[0], e0.x, s); s = fmaf(x8[1], e0.y, s);
                s = fmaf(x8[2], e0.z, s); s = fmaf(x8[3], e0.w, s);
                s = fmaf(x8[4], e1.x, s); s = fmaf(x8[5], e1.y, s);
                s = fmaf(x8[6], e1.z, s); s = fmaf(x8[7], e1.w, s);
                Sp[rr][c] = s;
            }
        }
    }

    // ---- per-row group-reduce + best-of-4 + idx/counts/loss
    float lracc = 0.f;
#pragma unroll
    for (int rr = 0; rr < 8; ++rr) {
        const int r = g16 * 8 + rr;
        float s0 = Sp[rr][0], s1 = Sp[rr][1], s2 = Sp[rr][2], s3 = Sp[rr][3];
        float x2v = X2r[rr];
#pragma unroll
        for (int off = 1; off < 16; off <<= 1) {
            s0 += __shfl_xor(s0, off); s1 += __shfl_xor(s1, off);
            s2 += __shfl_xor(s2, off); s3 += __shfl_xor(s3, off);
            x2v += __shfl_xor(x2v, off);
        }
        const float4 Ac = red[r * 2];
        const float4 Bc = red[r * 2 + 1];
        const int cid[4] = {__float_as_int(Ac.y), __float_as_int(Ac.w),
                            __float_as_int(Bc.y), __float_as_int(Bc.w)};
        const float S4[4] = {s0, s1, s2, s3};
        float bv = 3.402823466e38f; int bi = 0; float sb = 0.f, eb = 0.f;
#pragma unroll
        for (int k = 0; k < 4; ++k) {
            const float ev = e2g[cid[k]];
            const float dv = fmaf(-2.0f, S4[k], ev);
            if (dv < bv || (dv == bv && cid[k] < bi)) { bv = dv; bi = cid[k]; sb = S4[k]; eb = ev; }
        }
        if (lm == rr) {
            idx_g[n0 + r] = bi;
            atomicAdd(&counts[bi], 1);
            lracc = x2v - 2.0f * sb + eb;   // ||x - q||^2 for row r
        }
    }
#pragma unroll
    for (int off = 32; off >= 1; off >>= 1) lracc += __shfl_down(lracc, off);
    if (lane == 0) atomicAdd(lsum, lracc);
    __syncthreads();
    if (tid == 0) atomicAdd(sumsq, *lsum);
}

// ------------------------------------------------ output kernel: COALESCED emb gather
// through LDS + transposed coalesced outQ stores + one-hot encodings. Block = 32 rows.
__launch_bounds__(256)
__global__ void k_out(const float* __restrict__ emb, const int* __restrict__ idx_g,
                      float* __restrict__ outQ, float* __restrict__ enc) {
    __shared__ __align__(16) float Qs[32][260];   // 33.3 KB
    __shared__ int idxs[32];
    const int blk = blockIdx.x;            // 2048 blocks
    const int b   = blk >> 7;
    const int hw0 = (blk & 127) << 5;
    const int tid = threadIdx.x;
    const int w = tid >> 6, lane = tid & 63;
    const int g = tid >> 4, lm = tid & 15;
    const int n0 = (b << 12) + hw0;

    if (tid < 32) idxs[tid] = idx_g[n0 + tid];
    __syncthreads();

    // stage Q rows coalesced: group g -> rows 2g, 2g+1; lane lm covers 16 d (64B)
#pragma unroll
    for (int rr = 0; rr < 2; ++rr) {
        const int r = g * 2 + rr;
        const float* ep = emb + (size_t)idxs[r] * DDIM + lm * 16;
#pragma unroll
        for (int j = 0; j < 4; ++j)
            *(float4*)&Qs[r][lm * 16 + j * 4] = *(const float4*)(ep + j * 4);
    }
    __syncthreads();

    // outQ[d][hw]: coalesced nt stores (2 x 128B segments per instr)
    float* op = outQ + (size_t)b * 1048576 + hw0;
    const int dh = lane >> 5, hl = lane & 31;
#pragma unroll 8
    for (int dd = 0; dd < 32; ++dd) {
        const int d = w * 64 + dd * 2 + dh;
        __builtin_nontemporal_store(Qs[hl][d], op + (size_t)d * 4096 + hl);
    }

    // one-hot encodings (32 rows x 8 KB), 8B f32x2 nt stores
    f32x2* erow = (f32x2*)enc + (size_t)n0 * 1024;
#pragma unroll 1
    for (int rr = 0; rr < 32; ++rr) {
        const int id = idxs[rr];
        f32x2* rp = erow + (size_t)rr * 1024;
#pragma unroll
        for (int k = 0; k < 4; ++k) {
            const int c2 = k * 256 + tid;
            const int ccc = c2 * 2;
            f32x2 v;
            v[0] = (ccc == id) ? 1.0f : 0.0f;
            v[1] = (ccc + 1 == id) ? 1.0f : 0.0f;
            __builtin_nontemporal_store(v, rp + c2);
        }
    }
}

// ------------------------------------------------ scalars
__launch_bounds__(256)
__global__ void k_finalize(const int* __restrict__ counts, const float* __restrict__ sumsq,
                           float* __restrict__ out) {
    __shared__ float red[256];
    const int t = threadIdx.x;
    float s = 0.0f;
    for (int k = t; k < KCODES; k += 256) {
        const float p = (float)counts[k] * (1.0f / 65536.0f);
        s += p * logf(p + 1e-10f);
    }
    red[t] = s;
    __syncthreads();
    for (int off = 128; off >= 1; off >>= 1) {
        if (t < off) red[t] += red[t + off];
        __syncthreads();
    }
    if (t == 0) {
        out[OUT_PERP] = expf(-red[0]);
        out[OUT_LOSS] = 0.25f * sumsq[0] * (1.0f / 16777216.0f);
    }
}

// ------------------------------------------------ launch
extern "C" void kernel_launch(void* const* d_in, const int* in_sizes, int n_in,
                              void* d_out, int out_size, void* d_ws, size_t ws_size,
                              hipStream_t stream) {
    const float* inp = (const float*)d_in[0];
    const float* emb = (const float*)d_in[1];
    float* out = (float*)d_out;
    char* wsb  = (char*)d_ws;

    int*      idxg   = (int*)(wsb + WS_IDX);
    float*    e2     = (float*)(wsb + WS_E2);
    int*      counts = (int*)(wsb + WS_CNT);
    float*    sumsq  = (float*)(wsb + WS_SUM);
    _Float16* Ehi    = (_Float16*)(wsb + WS_EHI);

    k_e2split <<<512,  256, 0, stream>>>(emb, Ehi, e2, counts, sumsq);
    k_main    <<<512,  256, 0, stream>>>(inp, emb, Ehi, e2, idxg, counts, sumsq);
    k_out     <<<2048, 256, 0, stream>>>(emb, idxg, out + OUT_Q, out + OUT_ENC);
    k_finalize<<<1,    256, 0, stream>>>(counts, sumsq, out);
}

// Round 5
// 853.971 us; speedup vs baseline: 1.1448x; 1.0048x over previous
//
#include <hip/hip_runtime.h>

// Problem: inputs [16,256,64,64] f32, embedding [2048,256] f32
#define KCODES  2048
#define DDIM    256

// d_out float-element offsets (return order: loss, quantized, perplexity, encodings)
#define OUT_LOSS 0
#define OUT_Q    1
#define OUT_PERP 16777217
#define OUT_ENC  16777218

// d_ws byte offsets
#define WS_E2   1048576        // float e2[2048]          (8 KB)
#define WS_CNT  1056768        // int   counts[2048]      (8 KB)
#define WS_SUM  1064960        // float sumsq[1]
#define WS_EHI  2097152        // _Float16 Ehi[2048*256]  (1 MiB)

typedef _Float16 f16x8 __attribute__((ext_vector_type(8)));
typedef _Float16 f16x4 __attribute__((ext_vector_type(4)));
typedef float    f32x4 __attribute__((ext_vector_type(4)));
typedef float    f32x2 __attribute__((ext_vector_type(2)));

__device__ __forceinline__ void gld16(const void* g, void* l) {
    __builtin_amdgcn_global_load_lds((const __attribute__((address_space(1))) void*)g,
                                     (__attribute__((address_space(3))) void*)l, 16, 0, 0);
}

// top-2 pair merge with idx tie-break (lower idx wins)
#define MERGE2(m1,i1,m2,i2,n1,j1,n2,j2)                                   \
    {                                                                     \
        const bool w_ = ((n1) < (m1)) || ((n1) == (m1) && (j1) < (i1));   \
        const float w1_ = w_ ? (n1) : (m1); const int wi_ = w_ ? (j1) : (i1); \
        const float l1_ = w_ ? (m1) : (n1); const int li_ = w_ ? (i1) : (j1); \
        const float c2_ = w_ ? (n2) : (m2); const int ci_ = w_ ? (j2) : (i2); \
        const bool s_ = ((c2_) < (l1_)) || ((c2_) == (l1_) && (ci_) < (li_)); \
        (m1) = w1_; (i1) = wi_;                                           \
        (m2) = s_ ? c2_ : l1_; (i2) = s_ ? ci_ : li_;                     \
    }

// ------------------------------------------------ Ehi + ||e||^2 + zero counts/sumsq
__launch_bounds__(256)
__global__ void k_e2split(const float* __restrict__ emb, _Float16* __restrict__ Ehi,
                          float* __restrict__ e2, int* __restrict__ counts,
                          float* __restrict__ sumsq) {
    const int wave = threadIdx.x >> 6;
    const int lane = threadIdx.x & 63;
    const int k = blockIdx.x * 4 + wave;          // 512 blocks
    const float4 v = *(const float4*)(emb + k * DDIM + lane * 4);
    f16x4 h;
    h[0] = (_Float16)v.x; h[1] = (_Float16)v.y; h[2] = (_Float16)v.z; h[3] = (_Float16)v.w;
    *(f16x4*)(Ehi + k * DDIM + lane * 4) = h;
    float s = v.x * v.x + v.y * v.y + v.z * v.z + v.w * v.w;
#pragma unroll
    for (int off = 32; off >= 1; off >>= 1) s += __shfl_down(s, off);
    if (lane == 0) e2[k] = s;
    if (blockIdx.x < 8) counts[blockIdx.x * 256 + threadIdx.x] = 0;
    if (blockIdx.x == 8 && threadIdx.x == 0) sumsq[0] = 0.0f;
}

// ------------------------------------------------ fully fused main: f16 A-plane in-LDS +
// approx top-4 (MFMA) + coalesced exact refine + argmin + loss + counts + ALL outputs
// (one-hot enc stream + LDS-staged coalesced quantized). One block = 128 rows.
__launch_bounds__(256, 2)
__global__ void k_main(const float* __restrict__ inp, const float* __restrict__ emb,
                       const _Float16* __restrict__ Ehi, const float* __restrict__ e2g,
                       int* __restrict__ counts, float* __restrict__ sumsq,
                       float* __restrict__ outQ, float* __restrict__ encQ) {
    __shared__ __align__(16) char pool[81920];        // 80 KB union
    _Float16* A  = (_Float16*)pool;                   // [128*256] f16, 64 KB (GEMM phase)
    _Float16* Bh = (_Float16*)(pool + 65536);         // [128*64]  f16, 16 KB (GEMM phase)

    const int rb  = blockIdx.x;           // 512 blocks of 128 rows
    const int b   = rb >> 5;
    const int hw0 = (rb & 31) << 7;
    const int n0  = rb << 7;
    const int tid = threadIdx.x;
    const int w = tid >> 6, lane = tid & 63;
    const int lq = lane >> 4, lm = lane & 15;
    const int wr = (w >> 1) * 64, wc = (w & 1) * 64;  // wave quadrant
    const int r8 = lane >> 3, c8 = lane & 7;
    const int gch = c8 ^ r8;              // XOR-swizzled source chunk for B staging

    // ---- prologue: inp[b, d, hw0+row] f32 -> swizzled f16 A[row][d]. Coalesced 256B loads.
    const float* base = inp + (size_t)b * 1048576 + hw0;
#pragma unroll 4
    for (int rr = 0; rr < 16; ++rr) {
        const int row = ((rr & 1) << 6) + lane;
        const int cg  = ((rr >> 1) << 2) + w;
        const float* p = base + (size_t)(cg << 3) * 4096 + row;
        float v[8];
#pragma unroll
        for (int j = 0; j < 8; ++j) v[j] = p[(size_t)j * 4096];
        f16x8 h;
#pragma unroll
        for (int j = 0; j < 8; ++j) h[j] = (_Float16)v[j];
        const int q  = cg >> 3;            // 64-d quarter
        const int ch = cg & 7;             // chunk within quarter
        *(f16x8*)&A[row * 256 + q * 64 + ((ch ^ (row & 7)) << 3)] = h;
    }
    __syncthreads();

    // ---- main loop: 16 col-tiles x 128 cols. A persistent LDS; B staged per-kt via
    // global_load_lds (pre-swizzled source, linear LDS dest), 2 barriers/kt.
    const int sw0 = ((lq    ) ^ (lm & 7)) << 3;   // s=0 A-fragment swizzle
    const int sw1 = ((lq ^ 4) ^ (lm & 7)) << 3;   // s=1

    float V1[4][4], V2[4][4]; int I1[4][4], I2[4][4];
#pragma unroll
    for (int i = 0; i < 4; ++i)
#pragma unroll
        for (int rr = 0; rr < 4; ++rr) {
            V1[i][rr] = 3.402823466e38f; V2[i][rr] = 3.402823466e38f;
            I1[i][rr] = 0x7fffffff;      I2[i][rr] = 0x7fffffff;
        }

#pragma unroll 1
    for (int ct = 0; ct < 16; ++ct) {
        const int c0 = ct * 128;
        float e2v[4];
#pragma unroll
        for (int j = 0; j < 4; ++j) e2v[j] = e2g[c0 + wc + j * 16 + lm];

        f32x4 acc[4][4];
#pragma unroll
        for (int i = 0; i < 4; ++i)
#pragma unroll
            for (int j = 0; j < 4; ++j) acc[i][j] = (f32x4)(0.0f);

#pragma unroll 1
        for (int kt = 0; kt < 4; ++kt) {
            const int d0 = kt * 64;
            __syncthreads();
#pragma unroll
            for (int i = 0; i < 4; ++i) {
                const int Row = i * 32 + w * 8 + r8;
                gld16(Ehi + (size_t)(c0 + Row) * DDIM + d0 + gch * 8, &Bh[(i * 32 + w * 8) * 64]);
            }
            __syncthreads();
#pragma unroll
            for (int s = 0; s < 2; ++s) {
                const int wch = s * 4 + lq;
                const int sw = s ? sw1 : sw0;
                f16x8 af[4], bf[4];
#pragma unroll
                for (int t = 0; t < 4; ++t) {
                    const int Rb = wc + t * 16 + lm;
                    af[t] = *(const f16x8*)&A[(wr + t * 16 + lm) * 256 + d0 + sw];
                    bf[t] = *(const f16x8*)&Bh[Rb * 64 + ((wch ^ (Rb & 7)) << 3)];
                }
#pragma unroll
                for (int i = 0; i < 4; ++i)
#pragma unroll
                    for (int j = 0; j < 4; ++j)
                        acc[i][j] = __builtin_amdgcn_mfma_f32_16x16x32_f16(af[i], bf[j], acc[i][j], 0, 0, 0);
            }
        }

        // per-ct epilogue: branch-free running top-2. C layout: col=lm, row=lq*4+reg.
#pragma unroll
        for (int i = 0; i < 4; ++i)
#pragma unroll
            for (int j = 0; j < 4; ++j) {
                const int idx = c0 + wc + j * 16 + lm;
#pragma unroll
                for (int rr = 0; rr < 4; ++rr) {
                    const float dist = fmaf(-2.0f, acc[i][j][rr], e2v[j]);
                    const bool b1 = dist < V1[i][rr];
                    const bool b2 = dist < V2[i][rr];
                    V2[i][rr] = b1 ? V1[i][rr] : (b2 ? dist : V2[i][rr]);
                    I2[i][rr] = b1 ? I1[i][rr] : (b2 ? idx  : I2[i][rr]);
                    V1[i][rr] = b1 ? dist : V1[i][rr];
                    I1[i][rr] = b1 ? idx  : I1[i][rr];
                }
            }
    }

    __syncthreads();                       // GEMM LDS reads done -> pool reusable
    float4* red  = (float4*)pool;          // [128][2] candidate pairs (4 KB)
    int*    idxs = (int*)(pool + 4096);    // [128] final indices (512 B)
    float*  lsum = (float*)(pool + 4608);  // block loss accumulator
    float*  xf   = (float*)(pool + 8192);  // [128 dloc][129 rows] f32 (66 KB)
#pragma unroll
    for (int i = 0; i < 4; ++i)
#pragma unroll
        for (int rr = 0; rr < 4; ++rr) {
            float m1 = V1[i][rr]; int i1 = I1[i][rr];
            float m2 = V2[i][rr]; int i2 = I2[i][rr];
#pragma unroll
            for (int off = 1; off < 16; off <<= 1) {
                const float n1 = __shfl_xor(m1, off); const int j1 = __shfl_xor(i1, off);
                const float n2 = __shfl_xor(m2, off); const int j2 = __shfl_xor(i2, off);
                MERGE2(m1, i1, m2, i2, n1, j1, n2, j2);
            }
            if (lm == 0) {
                const int row = wr + i * 16 + lq * 4 + rr;
                red[row * 2 + (w & 1)] = make_float4(m1, __int_as_float(i1),
                                                     m2, __int_as_float(i2));
            }
        }
    if (tid == 0) *lsum = 0.f;

    // ---- COALESCED exact refine: 16-lane group per row; lane lm covers d-chunk lm*8..+7.
    const int g16 = tid >> 4;              // 16 groups, each owns rows g16*8 .. +7
    float Sp[8][4], X2r[8];
#pragma unroll
    for (int rr = 0; rr < 8; ++rr) {
        X2r[rr] = 0.f;
#pragma unroll
        for (int c = 0; c < 4; ++c) Sp[rr][c] = 0.f;
    }

#pragma unroll 1
    for (int h = 0; h < 2; ++h) {
        __syncthreads();                   // prev phase reads done (merge / h=0 compute)
#pragma unroll 8
        for (int k2 = 0; k2 < 32; ++k2) {
            const int dloc = w * 32 + k2;
            const float* sp = base + (size_t)(h * 128 + dloc) * 4096;
            xf[dloc * 129 + lane]      = sp[lane];
            xf[dloc * 129 + 64 + lane] = sp[64 + lane];
        }
        __syncthreads();
#pragma unroll
        for (int rr = 0; rr < 8; ++rr) {
            const int r = g16 * 8 + rr;
            const float4 Ac = red[r * 2];
            const float4 Bc = red[r * 2 + 1];
            const int cid[4] = {__float_as_int(Ac.y), __float_as_int(Ac.w),
                                __float_as_int(Bc.y), __float_as_int(Bc.w)};
            float x8[8];
#pragma unroll
            for (int j = 0; j < 8; ++j) x8[j] = xf[(lm * 8 + j) * 129 + r];
#pragma unroll
            for (int j = 0; j < 8; ++j) X2r[rr] = fmaf(x8[j], x8[j], X2r[rr]);
#pragma unroll
            for (int c = 0; c < 4; ++c) {
                const float* ep = emb + (size_t)cid[c] * DDIM + h * 128 + lm * 8;
                const float4 e0 = *(const float4*)ep;
                const float4 e1 = *(const float4*)(ep + 4);
                float s = Sp[rr][c];
                s = fmaf(x8[0], e0.x, s); s = fmaf(x8[1], e0.y, s);
                s = fmaf(x8[2], e0.z, s); s = fmaf(x8[3], e0.w, s);
                s = fmaf(x8[4], e1.x, s); s = fmaf(x8[5], e1.y, s);
                s = fmaf(x8[6], e1.z, s); s = fmaf(x8[7], e1.w, s);
                Sp[rr][c] = s;
            }
        }
    }

    // ---- per-row group-reduce + best-of-4 + idxs/counts/loss
    float lracc = 0.f;
#pragma unroll
    for (int rr = 0; rr < 8; ++rr) {
        const int r = g16 * 8 + rr;
        float s0 = Sp[rr][0], s1 = Sp[rr][1], s2 = Sp[rr][2], s3 = Sp[rr][3];
        float x2v = X2r[rr];
#pragma unroll
        for (int off = 1; off < 16; off <<= 1) {
            s0 += __shfl_xor(s0, off); s1 += __shfl_xor(s1, off);
            s2 += __shfl_xor(s2, off); s3 += __shfl_xor(s3, off);
            x2v += __shfl_xor(x2v, off);
        }
        const float4 Ac = red[r * 2];
        const float4 Bc = red[r * 2 + 1];
        const int cid[4] = {__float_as_int(Ac.y), __float_as_int(Ac.w),
                            __float_as_int(Bc.y), __float_as_int(Bc.w)};
        const float S4[4] = {s0, s1, s2, s3};
        float bv = 3.402823466e38f; int bi = 0; float sb = 0.f, eb = 0.f;
#pragma unroll
        for (int k = 0; k < 4; ++k) {
            const float ev = e2g[cid[k]];
            const float dv = fmaf(-2.0f, S4[k], ev);
            if (dv < bv || (dv == bv && cid[k] < bi)) { bv = dv; bi = cid[k]; sb = S4[k]; eb = ev; }
        }
        if (lm == rr) {
            idxs[r] = bi;
            atomicAdd(&counts[bi], 1);
            lracc = x2v - 2.0f * sb + eb;   // ||x - q||^2 for row r
        }
    }
#pragma unroll
    for (int off = 32; off >= 1; off >>= 1) lracc += __shfl_down(lracc, off);
    if (lane == 0) atomicAdd(lsum, lracc);
    __syncthreads();                        // idxs + lsum visible; xf dead
    if (tid == 0) atomicAdd(sumsq, *lsum);

    // ---- phase 4a: one-hot encodings (128 rows x 8 KB), nt f32x2 streams
    f32x2* erow = (f32x2*)encQ + (size_t)n0 * 1024;
#pragma unroll 1
    for (int rr = 0; rr < 128; ++rr) {
        const int id = idxs[rr];
        f32x2* rp = erow + (size_t)rr * 1024;
#pragma unroll
        for (int k = 0; k < 4; ++k) {
            const int c2 = k * 256 + tid;
            const int ccc = c2 * 2;
            f32x2 v;
            v[0] = (ccc == id) ? 1.0f : 0.0f;
            v[1] = (ccc + 1 == id) ? 1.0f : 0.0f;
            __builtin_nontemporal_store(v, rp + c2);
        }
    }

    // ---- phase 4b: quantized output, 4 chunks of 32 rows (LDS-staged, coalesced)
    float* Qs = (float*)(pool + 8192);      // [32][260] = 33 KB
    const int gq = tid >> 4, lmq = tid & 15;
#pragma unroll 1
    for (int c = 0; c < 4; ++c) {
        __syncthreads();                    // prev chunk's Qs reads done
#pragma unroll
        for (int rr2 = 0; rr2 < 2; ++rr2) {
            const int rl = gq * 2 + rr2;
            const float* ep = emb + (size_t)idxs[c * 32 + rl] * DDIM + lmq * 16;
#pragma unroll
            for (int j = 0; j < 4; ++j)
                *(float4*)&Qs[rl * 260 + lmq * 16 + j * 4] = *(const float4*)(ep + j * 4);
        }
        __syncthreads();
        float* op = outQ + (size_t)b * 1048576 + hw0 + c * 32;
        const int dh = lane >> 5, hl = lane & 31;
#pragma unroll 8
        for (int dd = 0; dd < 32; ++dd) {
            const int d = w * 64 + dd * 2 + dh;
            __builtin_nontemporal_store(Qs[hl * 260 + d], op + (size_t)d * 4096 + hl);
        }
    }
}

// ------------------------------------------------ scalars
__launch_bounds__(256)
__global__ void k_finalize(const int* __restrict__ counts, const float* __restrict__ sumsq,
                           float* __restrict__ out) {
    __shared__ float red[256];
    const int t = threadIdx.x;
    float s = 0.0f;
    for (int k = t; k < KCODES; k += 256) {
        const float p = (float)counts[k] * (1.0f / 65536.0f);
        s += p * logf(p + 1e-10f);
    }
    red[t] = s;
    __syncthreads();
    for (int off = 128; off >= 1; off >>= 1) {
        if (t < off) red[t] += red[t + off];
        __syncthreads();
    }
    if (t == 0) {
        out[OUT_PERP] = expf(-red[0]);
        out[OUT_LOSS] = 0.25f * sumsq[0] * (1.0f / 16777216.0f);
    }
}

// ------------------------------------------------ launch
extern "C" void kernel_launch(void* const* d_in, const int* in_sizes, int n_in,
                              void* d_out, int out_size, void* d_ws, size_t ws_size,
                              hipStream_t stream) {
    const float* inp = (const float*)d_in[0];
    const float* emb = (const float*)d_in[1];
    float* out = (float*)d_out;
    char* wsb  = (char*)d_ws;

    float*    e2     = (float*)(wsb + WS_E2);
    int*      counts = (int*)(wsb + WS_CNT);
    float*    sumsq  = (float*)(wsb + WS_SUM);
    _Float16* Ehi    = (_Float16*)(wsb + WS_EHI);

    k_e2split <<<512, 256, 0, stream>>>(emb, Ehi, e2, counts, sumsq);
    k_main    <<<512, 256, 0, stream>>>(inp, emb, Ehi, e2, counts, sumsq,
                                        out + OUT_Q, out + OUT_ENC);
    k_finalize<<<1,   256, 0, stream>>>(counts, sumsq, out);
}

// Round 7
// 835.138 us; speedup vs baseline: 1.1706x; 1.0226x over previous
//
#include <hip/hip_runtime.h>

// Problem: inputs [16,256,64,64] f32, embedding [2048,256] f32
#define KCODES  2048
#define DDIM    256

// d_out float-element offsets (return order: loss, quantized, perplexity, encodings)
#define OUT_LOSS 0
#define OUT_Q    1
#define OUT_PERP 16777217
#define OUT_ENC  16777218

// d_ws byte offsets
#define WS_E2   1048576        // float e2[2048]          (8 KB)
#define WS_CNT  1056768        // int   counts[2048]      (8 KB)
#define WS_SUM  1064960        // float sumsq[1]
#define WS_EHI  2097152        // _Float16 Ehi[2048*256]  (1 MiB)

typedef _Float16 f16x8 __attribute__((ext_vector_type(8)));
typedef _Float16 f16x4 __attribute__((ext_vector_type(4)));
typedef float    f32x4 __attribute__((ext_vector_type(4)));
typedef float    f32x2 __attribute__((ext_vector_type(2)));

__device__ __forceinline__ void gld16(const void* g, void* l) {
    __builtin_amdgcn_global_load_lds((const __attribute__((address_space(1))) void*)g,
                                     (__attribute__((address_space(3))) void*)l, 16, 0, 0);
}

// top-2 pair merge with idx tie-break (lower idx wins)
#define MERGE2(m1,i1,m2,i2,n1,j1,n2,j2)                                   \
    {                                                                     \
        const bool w_ = ((n1) < (m1)) || ((n1) == (m1) && (j1) < (i1));   \
        const float w1_ = w_ ? (n1) : (m1); const int wi_ = w_ ? (j1) : (i1); \
        const float l1_ = w_ ? (m1) : (n1); const int li_ = w_ ? (i1) : (j1); \
        const float c2_ = w_ ? (n2) : (m2); const int ci_ = w_ ? (j2) : (i2); \
        const bool s_ = ((c2_) < (l1_)) || ((c2_) == (l1_) && (ci_) < (li_)); \
        (m1) = w1_; (i1) = wi_;                                           \
        (m2) = s_ ? c2_ : l1_; (i2) = s_ ? ci_ : li_;                     \
    }

// ------------------------------------------------ Ehi + ||e||^2 + zero counts/sumsq
__launch_bounds__(256)
__global__ void k_e2split(const float* __restrict__ emb, _Float16* __restrict__ Ehi,
                          float* __restrict__ e2, int* __restrict__ counts,
                          float* __restrict__ sumsq) {
    const int wave = threadIdx.x >> 6;
    const int lane = threadIdx.x & 63;
    const int k = blockIdx.x * 4 + wave;          // 512 blocks
    const float4 v = *(const float4*)(emb + k * DDIM + lane * 4);
    f16x4 h;
    h[0] = (_Float16)v.x; h[1] = (_Float16)v.y; h[2] = (_Float16)v.z; h[3] = (_Float16)v.w;
    *(f16x4*)(Ehi + k * DDIM + lane * 4) = h;
    float s = v.x * v.x + v.y * v.y + v.z * v.z + v.w * v.w;
#pragma unroll
    for (int off = 32; off >= 1; off >>= 1) s += __shfl_down(s, off);
    if (lane == 0) e2[k] = s;
    if (blockIdx.x < 8) counts[blockIdx.x * 256 + threadIdx.x] = 0;
    if (blockIdx.x == 8 && threadIdx.x == 0) sumsq[0] = 0.0f;
}

// ------------------------------------------------ fused main, BM=64: A resident (32 KB) +
// DOUBLE-BUFFERED B staging (2x16 KB, one barrier per K-step, drains hidden under MFMA) +
// coalesced exact refine (conflict-free xf[row][129]) + argmin + loss + counts + outputs.
// 1024 blocks of 64 rows (4 rounds/CU -> phase skew/overlap).
__launch_bounds__(256, 2)
__global__ void k_main(const float* __restrict__ inp, const float* __restrict__ emb,
                       const _Float16* __restrict__ Ehi, const float* __restrict__ e2g,
                       int* __restrict__ counts, float* __restrict__ sumsq,
                       float* __restrict__ outQ, float* __restrict__ encQ) {
    __shared__ __align__(16) char pool[65536];        // 64 KB union -> 2 blocks/CU
    _Float16* A   = (_Float16*)pool;                  // [64*256] f16, 32 KB
    _Float16* Bh0 = (_Float16*)(pool + 32768);        // [128*64] f16, 16 KB
    _Float16* Bh1 = (_Float16*)(pool + 49152);        // [128*64] f16, 16 KB

    const int rb  = blockIdx.x;           // 1024 blocks of 64 rows
    const int b   = rb >> 6;
    const int hw0 = (rb & 63) << 6;
    const int n0  = rb << 6;
    const int tid = threadIdx.x;
    const int w = tid >> 6, lane = tid & 63;
    const int lq = lane >> 4, lm = lane & 15;
    const int wr = (w >> 1) * 32, wc = (w & 1) * 64;  // wave quadrant (M:2 x N:2)
    const int r8 = lane >> 3, c8 = lane & 7;
    const int gch = c8 ^ r8;              // XOR-swizzled source chunk for B staging

    // ---- prologue: inp[b, d, hw0+row] f32 -> swizzled f16 A[row][d]. Coalesced 256B loads.
    const float* base = inp + (size_t)b * 1048576 + hw0;
#pragma unroll 2
    for (int rr = 0; rr < 8; ++rr) {
        const int row = lane;              // 64 rows
        const int cg  = rr * 4 + w;        // 8-d chunk 0..31
        const float* p = base + (size_t)(cg << 3) * 4096 + row;
        float v[8];
#pragma unroll
        for (int j = 0; j < 8; ++j) v[j] = p[(size_t)j * 4096];
        f16x8 h;
#pragma unroll
        for (int j = 0; j < 8; ++j) h[j] = (_Float16)v[j];
        const int q  = cg >> 3;            // 64-d quarter
        const int ch = cg & 7;             // chunk within quarter
        *(f16x8*)&A[row * 256 + q * 64 + ((ch ^ (row & 7)) << 3)] = h;
    }

    // stage step 0 (ct0,kt0) into Bh0; A-barrier below drains it too
    {
#pragma unroll
        for (int i = 0; i < 4; ++i)
            gld16(Ehi + (size_t)(i * 32 + w * 8 + r8) * DDIM + gch * 8,
                  Bh0 + (i * 32 + w * 8) * 64);
    }
    __syncthreads();

    const int sw0 = ((lq    ) ^ (lm & 7)) << 3;   // s=0 A-fragment swizzle
    const int sw1 = ((lq ^ 4) ^ (lm & 7)) << 3;   // s=1

    float V1[2][4], V2[2][4]; int I1[2][4], I2[2][4];
#pragma unroll
    for (int i = 0; i < 2; ++i)
#pragma unroll
        for (int rr = 0; rr < 4; ++rr) {
            V1[i][rr] = 3.402823466e38f; V2[i][rr] = 3.402823466e38f;
            I1[i][rr] = 0x7fffffff;      I2[i][rr] = 0x7fffffff;
        }

    // ---- main loop: 64 steps (16 ct x 4 kt). One barrier/step; next-step stage issued
    // BEFORE compute so HBM/L2 latency hides under the 16 MFMAs (T3 minimum 2-phase).
    float e2v[4];
    f32x4 acc[2][4];
#pragma unroll 1
    for (int step = 0; step < 64; ++step) {
        const int ct = step >> 2, kt = step & 3;
        const int c0 = ct * 128, d0 = kt * 64;

        if (step < 63) {                   // stage step+1 into the other buffer
            const int ctn = (step + 1) >> 2, ktn = (step + 1) & 3;
            _Float16* bdst = ((step + 1) & 1) ? Bh1 : Bh0;
            const size_t soff = (size_t)(ctn * 128) * DDIM + ktn * 64 + gch * 8;
#pragma unroll
            for (int i = 0; i < 4; ++i)
                gld16(Ehi + soff + (size_t)(i * 32 + w * 8 + r8) * DDIM,
                      bdst + (i * 32 + w * 8) * 64);
        }
        if (kt == 0) {
#pragma unroll
            for (int j = 0; j < 4; ++j) e2v[j] = e2g[c0 + wc + j * 16 + lm];
#pragma unroll
            for (int i = 0; i < 2; ++i)
#pragma unroll
                for (int j = 0; j < 4; ++j) acc[i][j] = (f32x4)(0.0f);
        }

        const _Float16* Bc = (step & 1) ? Bh1 : Bh0;
#pragma unroll
        for (int s = 0; s < 2; ++s) {
            const int wch = s * 4 + lq;
            const int sw = s ? sw1 : sw0;
            f16x8 af[2], bf[4];
#pragma unroll
            for (int t = 0; t < 2; ++t)
                af[t] = *(const f16x8*)&A[(wr + t * 16 + lm) * 256 + d0 + sw];
#pragma unroll
            for (int t = 0; t < 4; ++t) {
                const int Rb = wc + t * 16 + lm;
                bf[t] = *(const f16x8*)&Bc[Rb * 64 + ((wch ^ (Rb & 7)) << 3)];
            }
#pragma unroll
            for (int i = 0; i < 2; ++i)
#pragma unroll
                for (int j = 0; j < 4; ++j)
                    acc[i][j] = __builtin_amdgcn_mfma_f32_16x16x32_f16(af[i], bf[j], acc[i][j], 0, 0, 0);
        }
        __syncthreads();                   // drains next-step stage; syncs Bc reads

        if (kt == 3) {
            // per-ct epilogue: branch-free running top-2. C layout: col=lm, row=lq*4+reg.
            // (overlaps other waves' next-ct compute; reads regs only)
#pragma unroll
            for (int i = 0; i < 2; ++i)
#pragma unroll
                for (int j = 0; j < 4; ++j) {
                    const int idx = c0 + wc + j * 16 + lm;
#pragma unroll
                    for (int rr = 0; rr < 4; ++rr) {
                        const float dist = fmaf(-2.0f, acc[i][j][rr], e2v[j]);
                        const bool b1 = dist < V1[i][rr];
                        const bool b2 = dist < V2[i][rr];
                        V2[i][rr] = b1 ? V1[i][rr] : (b2 ? dist : V2[i][rr]);
                        I2[i][rr] = b1 ? I1[i][rr] : (b2 ? idx  : I2[i][rr]);
                        V1[i][rr] = b1 ? dist : V1[i][rr];
                        I1[i][rr] = b1 ? idx  : I1[i][rr];
                    }
                }
        }
    }

    // ---- pool reuse: candidates + refine scratch
    float4* red  = (float4*)pool;          // [64][2] candidate pairs (2 KB)
    int*    idxs = (int*)(pool + 2048);    // [64] final indices
    float*  lsum = (float*)(pool + 2304);  // block loss accumulator
    float*  xf   = (float*)(pool + 4096);  // [64 rows][129 d] f32 (33 KB)
#pragma unroll
    for (int i = 0; i < 2; ++i)
#pragma unroll
        for (int rr = 0; rr < 4; ++rr) {
            float m1 = V1[i][rr]; int i1 = I1[i][rr];
            float m2 = V2[i][rr]; int i2 = I2[i][rr];
#pragma unroll
            for (int off = 1; off < 16; off <<= 1) {
                const float n1 = __shfl_xor(m1, off); const int j1 = __shfl_xor(i1, off);
                const float n2 = __shfl_xor(m2, off); const int j2 = __shfl_xor(i2, off);
                MERGE2(m1, i1, m2, i2, n1, j1, n2, j2);
            }
            if (lm == 0) {
                const int row = wr + i * 16 + lq * 4 + rr;
                red[row * 2 + (w & 1)] = make_float4(m1, __int_as_float(i1),
                                                     m2, __int_as_float(i2));
            }
        }
    if (tid == 0) *lsum = 0.f;

    // ---- COALESCED exact refine: 16-lane group per row; lane lm covers d-chunk lm*8..+7.
    // xf[row][129]: conflict-free scalar writes (bank=lane) and b128 reads (groups offset
    // by 8 banks). emb reads contiguous 512B per group.
    const int g16 = tid >> 4;              // 16 groups, each owns rows g16*4 .. +3
    float Sp[4][4], X2r[4];
#pragma unroll
    for (int rr = 0; rr < 4; ++rr) {
        X2r[rr] = 0.f;
#pragma unroll
        for (int c = 0; c < 4; ++c) Sp[rr][c] = 0.f;
    }

#pragma unroll 1
    for (int h = 0; h < 2; ++h) {
        __syncthreads();                   // merge writes visible / prev-h xf reads done
#pragma unroll 8
        for (int k2 = 0; k2 < 32; ++k2) {
            const int dloc = w * 32 + k2;
            const float* sp = base + (size_t)(h * 128 + dloc) * 4096;
            xf[lane * 129 + dloc] = sp[lane];          // row=lane, conflict-free
        }
        __syncthreads();
#pragma unroll
        for (int rr = 0; rr < 4; ++rr) {
            const int r = g16 * 4 + rr;
            const float4 Ac = red[r * 2];
            const float4 Bc4 = red[r * 2 + 1];
            const int cid[4] = {__float_as_int(Ac.y), __float_as_int(Ac.w),
                                __float_as_int(Bc4.y), __float_as_int(Bc4.w)};
            float x8[8];
            {
                const float4 xa = *(const float4*)&xf[r * 129 + lm * 8];
                const float4 xb = *(const float4*)&xf[r * 129 + lm * 8 + 4];
                x8[0] = xa.x; x8[1] = xa.y; x8[2] = xa.z; x8[3] = xa.w;
                x8[4] = xb.x; x8[5] = xb.y; x8[6] = xb.z; x8[7] = xb.w;
            }
#pragma unroll
            for (int j = 0; j < 8; ++j) X2r[rr] = fmaf(x8[j], x8[j], X2r[rr]);
#pragma unroll
            for (int c = 0; c < 4; ++c) {
                const float* ep = emb + (size_t)cid[c] * DDIM + h * 128 + lm * 8;
                const float4 e0 = *(const float4*)ep;
                const float4 e1 = *(const float4*)(ep + 4);
                float s = Sp[rr][c];
                s = fmaf(x8[0], e0.x, s); s = fmaf(x8[1], e0.y, s);
                s = fmaf(x8[2], e0.z, s); s = fmaf(x8[3], e0.w, s);
                s = fmaf(x8[4], e1.x, s); s = fmaf(x8[5], e1.y, s);
                s = fmaf(x8[6], e1.z, s); s = fmaf(x8[7], e1.w, s);
                Sp[rr][c] = s;
            }
        }
    }

    // ---- per-row group-reduce + best-of-4 + idxs/counts/loss
    float lracc = 0.f;
#pragma unroll
    for (int rr = 0; rr < 4; ++rr) {
        const int r = g16 * 4 + rr;
        float s0 = Sp[rr][0], s1 = Sp[rr][1], s2 = Sp[rr][2], s3 = Sp[rr][3];
        float x2v = X2r[rr];
#pragma unroll
        for (int off = 1; off < 16; off <<= 1) {
            s0 += __shfl_xor(s0, off); s1 += __shfl_xor(s1, off);
            s2 += __shfl_xor(s2, off); s3 += __shfl_xor(s3, off);
            x2v += __shfl_xor(x2v, off);
        }
        const float4 Ac = red[r * 2];
        const float4 Bc4 = red[r * 2 + 1];
        const int cid[4] = {__float_as_int(Ac.y), __float_as_int(Ac.w),
                            __float_as_int(Bc4.y), __float_as_int(Bc4.w)};
        const float S4[4] = {s0, s1, s2, s3};
        float bv = 3.402823466e38f; int bi = 0; float sb = 0.f, eb = 0.f;
#pragma unroll
        for (int k = 0; k < 4; ++k) {
            const float ev = e2g[cid[k]];
            const float dv = fmaf(-2.0f, S4[k], ev);
            if (dv < bv || (dv == bv && cid[k] < bi)) { bv = dv; bi = cid[k]; sb = S4[k]; eb = ev; }
        }
        if (lm == rr) {
            idxs[r] = bi;
            atomicAdd(&counts[bi], 1);
            lracc = x2v - 2.0f * sb + eb;   // ||x - q||^2 for row r
        }
    }
#pragma unroll
    for (int off = 32; off >= 1; off >>= 1) lracc += __shfl_down(lracc, off);
    if (lane == 0) atomicAdd(lsum, lracc);
    __syncthreads();                        // idxs + lsum visible; xf dead
    if (tid == 0) atomicAdd(sumsq, *lsum);

    // ---- phase 4a: one-hot encodings (64 rows x 8 KB), nt f32x2 streams
    f32x2* erow = (f32x2*)encQ + (size_t)n0 * 1024;
#pragma unroll 1
    for (int rr = 0; rr < 64; ++rr) {
        const int id = idxs[rr];
        f32x2* rp = erow + (size_t)rr * 1024;
#pragma unroll
        for (int k = 0; k < 4; ++k) {
            const int c2 = k * 256 + tid;
            const int ccc = c2 * 2;
            f32x2 v;
            v[0] = (ccc == id) ? 1.0f : 0.0f;
            v[1] = (ccc + 1 == id) ? 1.0f : 0.0f;
            __builtin_nontemporal_store(v, rp + c2);
        }
    }

    // ---- phase 4b: quantized output, 2 chunks of 32 rows (LDS-staged, coalesced)
    float* Qs = (float*)(pool + 4096);      // [32][260] = 33 KB (reuses xf)
    const int gq = tid >> 4, lmq = tid & 15;
#pragma unroll 1
    for (int c = 0; c < 2; ++c) {
        __syncthreads();                    // prev chunk's Qs reads done
#pragma unroll
        for (int rr2 = 0; rr2 < 2; ++rr2) {
            const int rl = gq * 2 + rr2;
            const float* ep = emb + (size_t)idxs[c * 32 + rl] * DDIM + lmq * 16;
#pragma unroll
            for (int j = 0; j < 4; ++j)
                *(float4*)&Qs[rl * 260 + lmq * 16 + j * 4] = *(const float4*)(ep + j * 4);
        }
        __syncthreads();
        float* op = outQ + (size_t)b * 1048576 + hw0 + c * 32;
        const int dh = lane >> 5, hl = lane & 31;
#pragma unroll 8
        for (int dd = 0; dd < 32; ++dd) {
            const int d = w * 64 + dd * 2 + dh;
            __builtin_nontemporal_store(Qs[hl * 260 + d], op + (size_t)d * 4096 + hl);
        }
    }
}

// ------------------------------------------------ scalars
__launch_bounds__(256)
__global__ void k_finalize(const int* __restrict__ counts, const float* __restrict__ sumsq,
                           float* __restrict__ out) {
    __shared__ float red[256];
    const int t = threadIdx.x;
    float s = 0.0f;
    for (int k = t; k < KCODES; k += 256) {
        const float p = (float)counts[k] * (1.0f / 65536.0f);
        s += p * logf(p + 1e-10f);
    }
    red[t] = s;
    __syncthreads();
    for (int off = 128; off >= 1; off >>= 1) {
        if (t < off) red[t] += red[t + off];
        __syncthreads();
    }
    if (t == 0) {
        out[OUT_PERP] = expf(-red[0]);
        out[OUT_LOSS] = 0.25f * sumsq[0] * (1.0f / 16777216.0f);
    }
}

// ------------------------------------------------ launch
extern "C" void kernel_launch(void* const* d_in, const int* in_sizes, int n_in,
                              void* d_out, int out_size, void* d_ws, size_t ws_size,
                              hipStream_t stream) {
    const float* inp = (const float*)d_in[0];
    const float* emb = (const float*)d_in[1];
    float* out = (float*)d_out;
    char* wsb  = (char*)d_ws;

    float*    e2     = (float*)(wsb + WS_E2);
    int*      counts = (int*)(wsb + WS_CNT);
    float*    sumsq  = (float*)(wsb + WS_SUM);
    _Float16* Ehi    = (_Float16*)(wsb + WS_EHI);

    k_e2split <<<512,  256, 0, stream>>>(emb, Ehi, e2, counts, sumsq);
    k_main    <<<1024, 256, 0, stream>>>(inp, emb, Ehi, e2, counts, sumsq,
                                         out + OUT_Q, out + OUT_ENC);
    k_finalize<<<1,    256, 0, stream>>>(counts, sumsq, out);
}

// Round 8
// 829.107 us; speedup vs baseline: 1.1791x; 1.0073x over previous
//
#include <hip/hip_runtime.h>

// Problem: inputs [16,256,64,64] f32, embedding [2048,256] f32
#define KCODES  2048
#define DDIM    256

// d_out float-element offsets (return order: loss, quantized, perplexity, encodings)
#define OUT_LOSS 0
#define OUT_Q    1
#define OUT_PERP 16777217
#define OUT_ENC  16777218

// d_ws byte offsets
#define WS_E2   1048576        // float e2[2048]          (8 KB)
#define WS_CNT  1056768        // int   counts[2048]      (8 KB)
#define WS_SUM  1064960        // float sumsq[1]
#define WS_EHI  2097152        // _Float16 Ehi[2048*256]  (1 MiB)

typedef _Float16 f16x8 __attribute__((ext_vector_type(8)));
typedef _Float16 f16x4 __attribute__((ext_vector_type(4)));
typedef float    f32x4 __attribute__((ext_vector_type(4)));
typedef float    f32x2 __attribute__((ext_vector_type(2)));

__device__ __forceinline__ void gld16(const void* g, void* l) {
    __builtin_amdgcn_global_load_lds((const __attribute__((address_space(1))) void*)g,
                                     (__attribute__((address_space(3))) void*)l, 16, 0, 0);
}

// top-2 pair merge with idx tie-break (lower idx wins)
#define MERGE2(m1,i1,m2,i2,n1,j1,n2,j2)                                   \
    {                                                                     \
        const bool w_ = ((n1) < (m1)) || ((n1) == (m1) && (j1) < (i1));   \
        const float w1_ = w_ ? (n1) : (m1); const int wi_ = w_ ? (j1) : (i1); \
        const float l1_ = w_ ? (m1) : (n1); const int li_ = w_ ? (i1) : (j1); \
        const float c2_ = w_ ? (n2) : (m2); const int ci_ = w_ ? (j2) : (i2); \
        const bool s_ = ((c2_) < (l1_)) || ((c2_) == (l1_) && (ci_) < (li_)); \
        (m1) = w1_; (i1) = wi_;                                           \
        (m2) = s_ ? c2_ : l1_; (i2) = s_ ? ci_ : li_;                     \
    }

// ------------------------------------------------ Ehi + ||e||^2 + zero counts/sumsq
__launch_bounds__(256)
__global__ void k_e2split(const float* __restrict__ emb, _Float16* __restrict__ Ehi,
                          float* __restrict__ e2, int* __restrict__ counts,
                          float* __restrict__ sumsq) {
    const int wave = threadIdx.x >> 6;
    const int lane = threadIdx.x & 63;
    const int k = blockIdx.x * 4 + wave;          // 512 blocks
    const float4 v = *(const float4*)(emb + k * DDIM + lane * 4);
    f16x4 h;
    h[0] = (_Float16)v.x; h[1] = (_Float16)v.y; h[2] = (_Float16)v.z; h[3] = (_Float16)v.w;
    *(f16x4*)(Ehi + k * DDIM + lane * 4) = h;
    float s = v.x * v.x + v.y * v.y + v.z * v.z + v.w * v.w;
#pragma unroll
    for (int off = 32; off >= 1; off >>= 1) s += __shfl_down(s, off);
    if (lane == 0) e2[k] = s;
    if (blockIdx.x < 8) counts[blockIdx.x * 256 + threadIdx.x] = 0;
    if (blockIdx.x == 8 && threadIdx.x == 0) sumsq[0] = 0.0f;
}

// ------------------------------------------------ fused main, BM=64: A-fragments hoisted
// to REGISTERS (64 VGPR, loaded once -> main loop has zero A-LDS reads; LDS pipe was the
// limiter at 12 b128/step) + double-buffered B staging (one barrier/step) + coalesced
// exact refine + argmin + loss + counts + outputs. 1024 blocks of 64 rows.
__launch_bounds__(256, 2)
__global__ void k_main(const float* __restrict__ inp, const float* __restrict__ emb,
                       const _Float16* __restrict__ Ehi, const float* __restrict__ e2g,
                       int* __restrict__ counts, float* __restrict__ sumsq,
                       float* __restrict__ outQ, float* __restrict__ encQ) {
    __shared__ __align__(16) char pool[65536];        // 64 KB union -> 2 blocks/CU
    _Float16* A   = (_Float16*)pool;                  // [64*256] f16, 32 KB (prologue only)
    _Float16* Bh0 = (_Float16*)(pool + 32768);        // [128*64] f16, 16 KB
    _Float16* Bh1 = (_Float16*)(pool + 49152);        // [128*64] f16, 16 KB

    const int rb  = blockIdx.x;           // 1024 blocks of 64 rows
    const int b   = rb >> 6;
    const int hw0 = (rb & 63) << 6;
    const int n0  = rb << 6;
    const int tid = threadIdx.x;
    const int w = tid >> 6, lane = tid & 63;
    const int lq = lane >> 4, lm = lane & 15;
    const int wr = (w >> 1) * 32, wc = (w & 1) * 64;  // wave quadrant (M:2 x N:2)
    const int r8 = lane >> 3, c8 = lane & 7;
    const int gch = c8 ^ r8;              // XOR-swizzled source chunk for B staging

    // ---- prologue: inp[b, d, hw0+row] f32 -> swizzled f16 A[row][d]. Coalesced 256B loads.
    const float* base = inp + (size_t)b * 1048576 + hw0;
#pragma unroll 2
    for (int rr = 0; rr < 8; ++rr) {
        const int row = lane;              // 64 rows
        const int cg  = rr * 4 + w;        // 8-d chunk 0..31
        const float* p = base + (size_t)(cg << 3) * 4096 + row;
        float v[8];
#pragma unroll
        for (int j = 0; j < 8; ++j) v[j] = p[(size_t)j * 4096];
        f16x8 h;
#pragma unroll
        for (int j = 0; j < 8; ++j) h[j] = (_Float16)v[j];
        const int q  = cg >> 3;            // 64-d quarter
        const int ch = cg & 7;             // chunk within quarter
        *(f16x8*)&A[row * 256 + q * 64 + ((ch ^ (row & 7)) << 3)] = h;
    }

    // stage step 0 (ct0,kt0) into Bh0; A-barrier below drains it too
    {
#pragma unroll
        for (int i = 0; i < 4; ++i)
            gld16(Ehi + (size_t)(i * 32 + w * 8 + r8) * DDIM + gch * 8,
                  Bh0 + (i * 32 + w * 8) * 64);
    }
    __syncthreads();

    const int sw0 = ((lq    ) ^ (lm & 7)) << 3;   // s=0 A-fragment swizzle
    const int sw1 = ((lq ^ 4) ^ (lm & 7)) << 3;   // s=1

    // ---- hoist ALL A-fragments to registers (depend on kt,s,t only -- NOT ct).
    // 16 x f16x8 = 64 VGPR; main loop then does zero A-LDS reads.
    f16x8 afr[4][2][2];
#pragma unroll
    for (int kt = 0; kt < 4; ++kt)
#pragma unroll
        for (int s = 0; s < 2; ++s) {
            const int sw = s ? sw1 : sw0;
#pragma unroll
            for (int t = 0; t < 2; ++t)
                afr[kt][s][t] = *(const f16x8*)&A[(wr + t * 16 + lm) * 256 + kt * 64 + sw];
        }

    float V1[2][4], V2[2][4]; int I1[2][4], I2[2][4];
#pragma unroll
    for (int i = 0; i < 2; ++i)
#pragma unroll
        for (int rr = 0; rr < 4; ++rr) {
            V1[i][rr] = 3.402823466e38f; V2[i][rr] = 3.402823466e38f;
            I1[i][rr] = 0x7fffffff;      I2[i][rr] = 0x7fffffff;
        }

    // ---- main loop: 16 ct x (unrolled kt 0..3). One barrier per (ct,kt) step; next-step
    // stage issued BEFORE compute so latency hides under MFMAs. kt compile-time -> afr
    // register-indexed statically (no scratch).
    float e2v[4];
    f32x4 acc[2][4];
#pragma unroll 1
    for (int ct = 0; ct < 16; ++ct) {
        const int c0 = ct * 128;
#pragma unroll
        for (int j = 0; j < 4; ++j) e2v[j] = e2g[c0 + wc + j * 16 + lm];
#pragma unroll
        for (int i = 0; i < 2; ++i)
#pragma unroll
            for (int j = 0; j < 4; ++j) acc[i][j] = (f32x4)(0.0f);

#pragma unroll
        for (int kt = 0; kt < 4; ++kt) {
            const int d0 = kt * 64; (void)d0;
            // stage next step: (ct, kt+1) for kt<3, (ct+1, 0) for kt==3 (skip at very end)
            if (kt < 3 || ct < 15) {
                const int ctn = (kt < 3) ? ct : ct + 1;
                const int ktn = (kt < 3) ? kt + 1 : 0;
                _Float16* bdst = ((kt + 1) & 1) ? Bh1 : Bh0;
                const size_t soff = (size_t)(ctn * 128) * DDIM + ktn * 64 + gch * 8;
#pragma unroll
                for (int i = 0; i < 4; ++i)
                    gld16(Ehi + soff + (size_t)(i * 32 + w * 8 + r8) * DDIM,
                          bdst + (i * 32 + w * 8) * 64);
            }

            const _Float16* Bc = (kt & 1) ? Bh1 : Bh0;
#pragma unroll
            for (int s = 0; s < 2; ++s) {
                const int wch = s * 4 + lq;
                f16x8 bf[4];
#pragma unroll
                for (int t = 0; t < 4; ++t) {
                    const int Rb = wc + t * 16 + lm;
                    bf[t] = *(const f16x8*)&Bc[Rb * 64 + ((wch ^ (Rb & 7)) << 3)];
                }
#pragma unroll
                for (int i = 0; i < 2; ++i)
#pragma unroll
                    for (int j = 0; j < 4; ++j)
                        acc[i][j] = __builtin_amdgcn_mfma_f32_16x16x32_f16(afr[kt][s][i], bf[j], acc[i][j], 0, 0, 0);
            }
            __syncthreads();               // drains next-step stage; syncs Bc reads
        }

        // per-ct epilogue: branch-free running top-2. C layout: col=lm, row=lq*4+reg.
#pragma unroll
        for (int i = 0; i < 2; ++i)
#pragma unroll
            for (int j = 0; j < 4; ++j) {
                const int idx = c0 + wc + j * 16 + lm;
#pragma unroll
                for (int rr = 0; rr < 4; ++rr) {
                    const float dist = fmaf(-2.0f, acc[i][j][rr], e2v[j]);
                    const bool b1 = dist < V1[i][rr];
                    const bool b2 = dist < V2[i][rr];
                    V2[i][rr] = b1 ? V1[i][rr] : (b2 ? dist : V2[i][rr]);
                    I2[i][rr] = b1 ? I1[i][rr] : (b2 ? idx  : I2[i][rr]);
                    V1[i][rr] = b1 ? dist : V1[i][rr];
                    I1[i][rr] = b1 ? idx  : I1[i][rr];
                }
            }
    }

    // ---- pool reuse: candidates + refine scratch
    float4* red  = (float4*)pool;          // [64][2] candidate pairs (2 KB)
    int*    idxs = (int*)(pool + 2048);    // [64] final indices
    float*  lsum = (float*)(pool + 2304);  // block loss accumulator
    float*  xf   = (float*)(pool + 4096);  // [64 rows][129 d] f32 (33 KB)
#pragma unroll
    for (int i = 0; i < 2; ++i)
#pragma unroll
        for (int rr = 0; rr < 4; ++rr) {
            float m1 = V1[i][rr]; int i1 = I1[i][rr];
            float m2 = V2[i][rr]; int i2 = I2[i][rr];
#pragma unroll
            for (int off = 1; off < 16; off <<= 1) {
                const float n1 = __shfl_xor(m1, off); const int j1 = __shfl_xor(i1, off);
                const float n2 = __shfl_xor(m2, off); const int j2 = __shfl_xor(i2, off);
                MERGE2(m1, i1, m2, i2, n1, j1, n2, j2);
            }
            if (lm == 0) {
                const int row = wr + i * 16 + lq * 4 + rr;
                red[row * 2 + (w & 1)] = make_float4(m1, __int_as_float(i1),
                                                     m2, __int_as_float(i2));
            }
        }
    if (tid == 0) *lsum = 0.f;

    // ---- COALESCED exact refine: 16-lane group per row; lane lm covers d-chunk lm*8..+7.
    // xf[row][129]: conflict-free scalar writes (bank=lane) and b128 reads (groups offset
    // by 8 banks). emb reads contiguous 512B per group.
    const int g16 = tid >> 4;              // 16 groups, each owns rows g16*4 .. +3
    float Sp[4][4], X2r[4];
#pragma unroll
    for (int rr = 0; rr < 4; ++rr) {
        X2r[rr] = 0.f;
#pragma unroll
        for (int c = 0; c < 4; ++c) Sp[rr][c] = 0.f;
    }

#pragma unroll 1
    for (int h = 0; h < 2; ++h) {
        __syncthreads();                   // merge writes visible / prev-h xf reads done
#pragma unroll 8
        for (int k2 = 0; k2 < 32; ++k2) {
            const int dloc = w * 32 + k2;
            const float* sp = base + (size_t)(h * 128 + dloc) * 4096;
            xf[lane * 129 + dloc] = sp[lane];          // row=lane, conflict-free
        }
        __syncthreads();
#pragma unroll
        for (int rr = 0; rr < 4; ++rr) {
            const int r = g16 * 4 + rr;
            const float4 Ac = red[r * 2];
            const float4 Bc4 = red[r * 2 + 1];
            const int cid[4] = {__float_as_int(Ac.y), __float_as_int(Ac.w),
                                __float_as_int(Bc4.y), __float_as_int(Bc4.w)};
            float x8[8];
            {
                const float4 xa = *(const float4*)&xf[r * 129 + lm * 8];
                const float4 xb = *(const float4*)&xf[r * 129 + lm * 8 + 4];
                x8[0] = xa.x; x8[1] = xa.y; x8[2] = xa.z; x8[3] = xa.w;
                x8[4] = xb.x; x8[5] = xb.y; x8[6] = xb.z; x8[7] = xb.w;
            }
#pragma unroll
            for (int j = 0; j < 8; ++j) X2r[rr] = fmaf(x8[j], x8[j], X2r[rr]);
#pragma unroll
            for (int c = 0; c < 4; ++c) {
                const float* ep = emb + (size_t)cid[c] * DDIM + h * 128 + lm * 8;
                const float4 e0 = *(const float4*)ep;
                const float4 e1 = *(const float4*)(ep + 4);
                float s = Sp[rr][c];
                s = fmaf(x8[0], e0.x, s); s = fmaf(x8[1], e0.y, s);
                s = fmaf(x8[2], e0.z, s); s = fmaf(x8[3], e0.w, s);
                s = fmaf(x8[4], e1.x, s); s = fmaf(x8[5], e1.y, s);
                s = fmaf(x8[6], e1.z, s); s = fmaf(x8[7], e1.w, s);
                Sp[rr][c] = s;
            }
        }
    }

    // ---- per-row group-reduce + best-of-4 + idxs/counts/loss
    float lracc = 0.f;
#pragma unroll
    for (int rr = 0; rr < 4; ++rr) {
        const int r = g16 * 4 + rr;
        float s0 = Sp[rr][0], s1 = Sp[rr][1], s2 = Sp[rr][2], s3 = Sp[rr][3];
        float x2v = X2r[rr];
#pragma unroll
        for (int off = 1; off < 16; off <<= 1) {
            s0 += __shfl_xor(s0, off); s1 += __shfl_xor(s1, off);
            s2 += __shfl_xor(s2, off); s3 += __shfl_xor(s3, off);
            x2v += __shfl_xor(x2v, off);
        }
        const float4 Ac = red[r * 2];
        const float4 Bc4 = red[r * 2 + 1];
        const int cid[4] = {__float_as_int(Ac.y), __float_as_int(Ac.w),
                            __float_as_int(Bc4.y), __float_as_int(Bc4.w)};
        const float S4[4] = {s0, s1, s2, s3};
        float bv = 3.402823466e38f; int bi = 0; float sb = 0.f, eb = 0.f;
#pragma unroll
        for (int k = 0; k < 4; ++k) {
            const float ev = e2g[cid[k]];
            const float dv = fmaf(-2.0f, S4[k], ev);
            if (dv < bv || (dv == bv && cid[k] < bi)) { bv = dv; bi = cid[k]; sb = S4[k]; eb = ev; }
        }
        if (lm == rr) {
            idxs[r] = bi;
            atomicAdd(&counts[bi], 1);
            lracc = x2v - 2.0f * sb + eb;   // ||x - q||^2 for row r
        }
    }
#pragma unroll
    for (int off = 32; off >= 1; off >>= 1) lracc += __shfl_down(lracc, off);
    if (lane == 0) atomicAdd(lsum, lracc);
    __syncthreads();                        // idxs + lsum visible; xf dead
    if (tid == 0) atomicAdd(sumsq, *lsum);

    // ---- phase 4a: one-hot encodings (64 rows x 8 KB), nt f32x2 streams
    f32x2* erow = (f32x2*)encQ + (size_t)n0 * 1024;
#pragma unroll 1
    for (int rr = 0; rr < 64; ++rr) {
        const int id = idxs[rr];
        f32x2* rp = erow + (size_t)rr * 1024;
#pragma unroll
        for (int k = 0; k < 4; ++k) {
            const int c2 = k * 256 + tid;
            const int ccc = c2 * 2;
            f32x2 v;
            v[0] = (ccc == id) ? 1.0f : 0.0f;
            v[1] = (ccc + 1 == id) ? 1.0f : 0.0f;
            __builtin_nontemporal_store(v, rp + c2);
        }
    }

    // ---- phase 4b: quantized output, 2 chunks of 32 rows (LDS-staged, coalesced)
    float* Qs = (float*)(pool + 4096);      // [32][260] = 33 KB (reuses xf)
    const int gq = tid >> 4, lmq = tid & 15;
#pragma unroll 1
    for (int c = 0; c < 2; ++c) {
        __syncthreads();                    // prev chunk's Qs reads done
#pragma unroll
        for (int rr2 = 0; rr2 < 2; ++rr2) {
            const int rl = gq * 2 + rr2;
            const float* ep = emb + (size_t)idxs[c * 32 + rl] * DDIM + lmq * 16;
#pragma unroll
            for (int j = 0; j < 4; ++j)
                *(float4*)&Qs[rl * 260 + lmq * 16 + j * 4] = *(const float4*)(ep + j * 4);
        }
        __syncthreads();
        float* op = outQ + (size_t)b * 1048576 + hw0 + c * 32;
        const int dh = lane >> 5, hl = lane & 31;
#pragma unroll 8
        for (int dd = 0; dd < 32; ++dd) {
            const int d = w * 64 + dd * 2 + dh;
            __builtin_nontemporal_store(Qs[hl * 260 + d], op + (size_t)d * 4096 + hl);
        }
    }
}

// ------------------------------------------------ scalars
__launch_bounds__(256)
__global__ void k_finalize(const int* __restrict__ counts, const float* __restrict__ sumsq,
                           float* __restrict__ out) {
    __shared__ float red[256];
    const int t = threadIdx.x;
    float s = 0.0f;
    for (int k = t; k < KCODES; k += 256) {
        const float p = (float)counts[k] * (1.0f / 65536.0f);
        s += p * logf(p + 1e-10f);
    }
    red[t] = s;
    __syncthreads();
    for (int off = 128; off >= 1; off >>= 1) {
        if (t < off) red[t] += red[t + off];
        __syncthreads();
    }
    if (t == 0) {
        out[OUT_PERP] = expf(-red[0]);
        out[OUT_LOSS] = 0.25f * sumsq[0] * (1.0f / 16777216.0f);
    }
}

// ------------------------------------------------ launch
extern "C" void kernel_launch(void* const* d_in, const int* in_sizes, int n_in,
                              void* d_out, int out_size, void* d_ws, size_t ws_size,
                              hipStream_t stream) {
    const float* inp = (const float*)d_in[0];
    const float* emb = (const float*)d_in[1];
    float* out = (float*)d_out;
    char* wsb  = (char*)d_ws;

    float*    e2     = (float*)(wsb + WS_E2);
    int*      counts = (int*)(wsb + WS_CNT);
    float*    sumsq  = (float*)(wsb + WS_SUM);
    _Float16* Ehi    = (_Float16*)(wsb + WS_EHI);

    k_e2split <<<512,  256, 0, stream>>>(emb, Ehi, e2, counts, sumsq);
    k_main    <<<1024, 256, 0, stream>>>(inp, emb, Ehi, e2, counts, sumsq,
                                         out + OUT_Q, out + OUT_ENC);
    k_finalize<<<1,    256, 0, stream>>>(counts, sumsq, out);
}